// Round 1
// baseline (16330.359 us; speedup 1.0000x reference)
//
#include <hip/hip_runtime.h>
#include <cstdint>
#include <cstddef>

namespace {
constexpr int T_ = 500, S_ = 32, B_ = 128, L_ = 64, R_ = 8;

__device__ __forceinline__ float wsum(float v) {
  v += __shfl_xor(v, 1);  v += __shfl_xor(v, 2);  v += __shfl_xor(v, 4);
  v += __shfl_xor(v, 8);  v += __shfl_xor(v, 16); v += __shfl_xor(v, 32);
  return v;
}

__device__ __forceinline__ void gload16(const float* g, float* l) {
  __builtin_amdgcn_global_load_lds((const __attribute__((address_space(1))) uint32_t*)g,
                                   (__attribute__((address_space(3))) uint32_t*)l,
                                   16, 0, 0);
}
}  // namespace

// One block per batch element b. 512 threads = 8 waves.
// LDS strides: Mc 33 (conflict-free rows+cols), z/g 68 (16B-aligned rows), ag 36.
__global__ __launch_bounds__(512, 2) void nlf_kernel(
    const float* __restrict__ m0p, const float* __restrict__ q0p,
    const float* __restrict__ qp,  const float* __restrict__ kp,
    const float* __restrict__ Kp,  const float* __restrict__ Ap,
    const float* __restrict__ wp0p, const float* __restrict__ wf0p,
    const float* __restrict__ wp1p, const float* __restrict__ wp2p,
    const float* __restrict__ wfp,  float* __restrict__ outp)
{
  __shared__ __align__(16) float z_s[S_*68];      // carry z / z_p_c
  __shared__ __align__(16) float g_s[S_*68];      // K@y1 per s
  __shared__ __align__(16) float Mc_s[L_*33];     // M_c[l][s]
  __shared__ __align__(16) float uni[1160];       // mp_part / C32+L / ag
  __shared__ __align__(16) float wp1b[2][S_*S_];
  __shared__ __align__(16) float wp2b[2][S_*L_];
  __shared__ __align__(16) float wf_s[S_*R_];
  __shared__ __align__(16) float Kt_s[L_*R_];
  __shared__ __align__(16) float v1t_s[S_*R_];
  __shared__ __align__(16) float KM_s[R_*33 + 3];
  __shared__ __align__(16) float M8_s[64];
  __shared__ __align__(16) float C8_s[64];
  __shared__ __align__(16) float rhs32_s[S_];
  __shared__ __align__(16) float y32_s[S_];
  __shared__ __align__(16) float th_s[S_];
  __shared__ __align__(16) float tg_s[S_];
  __shared__ __align__(16) float mf_s[L_];
  __shared__ __align__(16) float qv_s[L_];
  __shared__ __align__(16) float qiv_s[L_];
  __shared__ __align__(16) float q0v_s[L_];

  const int tid = threadIdx.x;
  const int lam = tid & 63;
  const int w   = tid >> 6;
  const int b   = blockIdx.x;

  // ---- persistent per-lane data: A row, Q vectors ----
  float Areg[64];
#pragma unroll
  for (int j4 = 0; j4 < 16; ++j4) {
    float4 a4 = *(const float4*)(Ap + (size_t)lam*64 + j4*4);
    Areg[4*j4+0]=a4.x; Areg[4*j4+1]=a4.y; Areg[4*j4+2]=a4.z; Areg[4*j4+3]=a4.w;
  }
  const float q_r  = qp[lam];
  const float qi_r = 1.0f / q_r;
  const float qs_r = sqrtf(q_r);
  const float q0_r = q0p[lam];
  const float m0_r = m0p[lam];
  if (tid < 64) { qv_s[tid] = q_r; qiv_s[tid] = qi_r; q0v_s[tid] = q0_r; }

  float Kreg[8];
  {
    const float* kb = Kp + (size_t)b*(L_*R_) + lam*R_;
    float4 ka = *(const float4*)kb, kb4 = *(const float4*)(kb+4);
    Kreg[0]=ka.x;Kreg[1]=ka.y;Kreg[2]=ka.z;Kreg[3]=ka.w;
    Kreg[4]=kb4.x;Kreg[5]=kb4.y;Kreg[6]=kb4.z;Kreg[7]=kb4.w;
  }
  float kt_r = kp[(size_t)b*L_ + lam];

  // ---- prologue async loads ----
  if (w == 0) {                       // wp1[0] -> wp1b[1]
#pragma unroll
    for (int m = 0; m < 4; ++m) {
      int f = m*256 + lam*4, s = f >> 5, c = f & 31;
      gload16(wp1p + ((size_t)s*B_ + b)*S_ + c, &wp1b[1][f]);
    }
  } else if (w == 1 || w == 2) {      // wp2[0] -> wp2b[1]
#pragma unroll
    for (int m = 0; m < 4; ++m) {
      int f = (w-1)*1024 + m*256 + lam*4, s = f >> 6, c = f & 63;
      gload16(wp2p + ((size_t)s*B_ + b)*L_ + c, &wp2b[1][f]);
    }
  } else if (w == 3) {                // wf0 -> wf_s ; K[0] -> Kt_s
    { int f = lam*4, s = f >> 3, c = f & 7;
      gload16(wf0p + ((size_t)s*B_ + b)*R_ + c, &wf_s[f]); }
#pragma unroll
    for (int m = 0; m < 2; ++m) {
      int f = m*256 + lam*4;
      gload16(Kp + (size_t)b*(L_*R_) + f, &Kt_s[f]);
    }
  } else if (w == 4 || w == 5) {      // w_p0 -> wp2b[0]
#pragma unroll
    for (int m = 0; m < 4; ++m) {
      int f = (w-4)*1024 + m*256 + lam*4, s = f >> 6, c = f & 63;
      gload16(wp0p + ((size_t)s*B_ + b)*L_ + c, &wp2b[0][f]);
    }
  }
  __syncthreads();

  // 8x8 SPD: C8_s -> M8_s = inv(C8) via in-register Cholesky (rows in lanes 0-7)
  auto chol8M8 = [&]() {
    const int i8 = lam & 7;
    float c8[8], rd8 = 0.0f;
#pragma unroll
    for (int k = 0; k < 8; ++k) c8[k] = C8_s[i8*8 + k];
#pragma unroll
    for (int j = 0; j < 8; ++j) {
      float dj = __shfl(c8[j], j);
      float rinv = rsqrtf(dj);
      if (i8 == j) rd8 = rinv;
      c8[j] *= rinv;
#pragma unroll
      for (int k = j+1; k < 8; ++k) {
        float Lkj = __shfl(c8[j], k);
        c8[k] = fmaf(-Lkj, c8[j], c8[k]);
      }
    }
    float w8[8];                       // lane holds column i8 of W = L^-1
#pragma unroll
    for (int i = 0; i < 8; ++i) {
      float sacc = (i == i8) ? 1.0f : 0.0f;
#pragma unroll
      for (int k = 0; k < i; ++k)
        sacc = fmaf(-__shfl(c8[k], i), w8[k], sacc);
      w8[i] = sacc * __shfl(rd8, i);
    }
#pragma unroll
    for (int i = 0; i < 8; ++i) {      // M8 = W^T W
      float msum = 0.0f;
#pragma unroll
      for (int k = 0; k < 8; ++k)
        msum = fmaf(__shfl(w8[k], i), w8[k], msum);
      if (lam < 8) M8_s[i*8 + lam] = msum;
    }
  };

  // ================= step 0 =================
  {
    const float Pp = q0_r;
    const float h0 = m0_r / Pp + kt_r;
    if (w == 0) {
      const int r1 = lam >> 3, r2 = lam & 7;
      float acc = 0.0f;
#pragma unroll 4
      for (int l = 0; l < 64; ++l)
        acc = fmaf(Kt_s[l*8 + r1] * q0v_s[l], Kt_s[l*8 + r2], acc);
      C8_s[lam] = acc + (r1 == r2 ? 1.0f : 0.0f);
      chol8M8();
      float t8[8];
#pragma unroll
      for (int r = 0; r < 8; ++r) t8[r] = wsum(Pp * Kreg[r] * h0);
      float acc2 = 0.0f;
#pragma unroll
      for (int r1i = 0; r1i < 8; ++r1i) {
        float4 ma = *(const float4*)&M8_s[r1i*8];
        float4 mb = *(const float4*)&M8_s[r1i*8+4];
        float y = ma.x*t8[0]+ma.y*t8[1]+ma.z*t8[2]+ma.w*t8[3]
                + mb.x*t8[4]+mb.y*t8[5]+mb.z*t8[6]+mb.w*t8[7];
        acc2 = fmaf(Kreg[r1i], y, acc2);
      }
      float m0f = Pp*h0 - Pp*acc2;
      mf_s[lam] = m0f;
      outp[(size_t)b*L_ + lam] = m0f;
    }
    __syncthreads();

    const float qs0 = sqrtf(q0_r);
#pragma unroll
    for (int i = 0; i < 4; ++i) {
      const int s = 4*w + i;
      float zp = qs0 * wp2b[0][s*64 + lam];
      float v1[8];
#pragma unroll
      for (int r = 0; r < 8; ++r)
        v1[r] = wsum(Kreg[r] * zp) + wf_s[s*8 + r];
      float acc = 0.0f;
#pragma unroll
      for (int r1i = 0; r1i < 8; ++r1i) {
        float4 ma = *(const float4*)&M8_s[r1i*8];
        float4 mb = *(const float4*)&M8_s[r1i*8+4];
        float y = ma.x*v1[0]+ma.y*v1[1]+ma.z*v1[2]+ma.w*v1[3]
                + mb.x*v1[4]+mb.y*v1[5]+mb.z*v1[6]+mb.w*v1[7];
        acc = fmaf(Kreg[r1i], y, acc);
      }
      z_s[s*68 + lam] = mf_s[lam] + zp - Pp*acc;
    }
  }
  __syncthreads();

  // ================= steps 1..T-1 =================
  for (int t = 1; t < T_; ++t) {
    const int cb = t & 1, nb = cb ^ 1;

    // ---- P0: async prefetch (next step wp1/wp2; this step wf/K) ----
    if (w == 0) {
      if (t < T_-1) {
#pragma unroll
        for (int m = 0; m < 4; ++m) {
          int f = m*256 + lam*4, s = f >> 5, c = f & 31;
          gload16(wp1p + (((size_t)t*S_ + s)*B_ + b)*S_ + c, &wp1b[nb][f]);
        }
      }
    } else if (w == 1 || w == 2) {
      if (t < T_-1) {
#pragma unroll
        for (int m = 0; m < 4; ++m) {
          int f = (w-1)*1024 + m*256 + lam*4, s = f >> 6, c = f & 63;
          gload16(wp2p + (((size_t)t*S_ + s)*B_ + b)*L_ + c, &wp2b[nb][f]);
        }
      }
    } else if (w == 3) {
      { int f = lam*4, s = f >> 3, c = f & 7;
        gload16(wfp + (((size_t)(t-1)*S_ + s)*B_ + b)*R_ + c, &wf_s[f]); }
#pragma unroll
      for (int m = 0; m < 2; ++m) {
        int f = m*256 + lam*4;
        gload16(Kp + ((size_t)t*B_ + b)*(L_*R_) + f, &Kt_s[f]);
      }
    }
    {
      const float* kb = Kp + ((size_t)t*B_ + b)*(L_*R_) + lam*R_;
      float4 ka = *(const float4*)kb, kb4 = *(const float4*)(kb+4);
      Kreg[0]=ka.x;Kreg[1]=ka.y;Kreg[2]=ka.z;Kreg[3]=ka.w;
      Kreg[4]=kb4.x;Kreg[5]=kb4.y;Kreg[6]=kb4.z;Kreg[7]=kb4.w;
      kt_r = kp[((size_t)t*B_ + b)*L_ + lam];
    }

    // ---- P1: dyn ----
    float zn[4];
#pragma unroll
    for (int i = 0; i < 4; ++i) {
      const int s = 4*w + i;
      float a0=0,a1=0,a2=0,a3=0;
#pragma unroll
      for (int j4 = 0; j4 < 16; ++j4) {
        float4 zb = *(const float4*)&z_s[s*68 + 4*j4];
        a0 = fmaf(zb.x, Areg[4*j4+0], a0);
        a1 = fmaf(zb.y, Areg[4*j4+1], a1);
        a2 = fmaf(zb.z, Areg[4*j4+2], a2);
        a3 = fmaf(zb.w, Areg[4*j4+3], a3);
      }
      float x = (a0+a1)+(a2+a3);
      float e = __expf(2.0f*x);
      float tnh = 1.0f - 2.0f/(e + 1.0f);
      zn[i] = z_s[s*68 + lam] + 0.1f*tnh;
    }
    uni[w*68 + lam] = zn[0]+zn[1]+zn[2]+zn[3];
    __syncthreads();  // B1

    // ---- P2: m_p, M_c, rhs32 = Mc^T u1, KM = K^T Mc ----
    float mp = 0.0f;
#pragma unroll
    for (int ww = 0; ww < 8; ++ww) mp += uni[ww*68 + lam];
    mp *= 0.03125f;
    const float u1 = qi_r * mp;
    float mcv[4];
#pragma unroll
    for (int i = 0; i < 4; ++i) {
      const int s = 4*w + i;
      mcv[i] = (zn[i] - mp) * 0.17677669529663689f;
      Mc_s[lam*33 + s] = mcv[i];
      float rv = wsum(mcv[i] * u1);
      if (lam == 0) rhs32_s[s] = rv;
      float kk = 0.0f;
#pragma unroll
      for (int r = 0; r < 8; ++r) {
        float km = wsum(mcv[i] * Kreg[r]);
        if (lam == r) kk = km;
      }
      if (lam < 8) KM_s[lam*33 + s] = kk;
    }
    __syncthreads();  // B2

    // ---- P3: G = Mc^T Qi Mc + I -> uni (stride 33) ----
    {
      const int s2 = lam & 31, hi = lam >> 5;
      const int s1a = 4*w + 2*hi, s1b = s1a + 1;
      float ga = 0, gb = 0;
#pragma unroll 4
      for (int l = 0; l < 64; ++l) {
        float mc2 = Mc_s[l*33 + s2];
        float tqm = qiv_s[l] * mc2;
        ga = fmaf(Mc_s[l*33 + s1a], tqm, ga);
        gb = fmaf(Mc_s[l*33 + s1b], tqm, gb);
      }
      if (s1a == s2) ga += 1.0f;
      if (s1b == s2) gb += 1.0f;
      uni[s1a*33 + s2] = ga;
      uni[s1b*33 + s2] = gb;
    }
    __syncthreads();  // B3

    // ---- P4: wave0 = 32x32 chol+solve; wave1 = 2 zp rows + KPK/chol8/M8;
    //          waves2-7 = 5 zp rows each ----
    auto zprow = [&](int s) {
      float acc = 0.0f;
#pragma unroll
      for (int p4 = 0; p4 < 32; p4 += 4) {
        float4 wb = *(const float4*)&wp1b[cb][s*32 + p4];
        acc = fmaf(Mc_s[lam*33 + p4+0], wb.x, acc);
        acc = fmaf(Mc_s[lam*33 + p4+1], wb.y, acc);
        acc = fmaf(Mc_s[lam*33 + p4+2], wb.z, acc);
        acc = fmaf(Mc_s[lam*33 + p4+3], wb.w, acc);
      }
      float zp = acc + qs_r * wp2b[cb][s*64 + lam];
      z_s[s*68 + lam] = zp;
      float vtmp = 0.0f;
#pragma unroll
      for (int r = 0; r < 8; ++r) {
        float vv = wsum(Kreg[r] * zp) + wf_s[s*8 + r];
        if (lam == r) vtmp = vv;
      }
      if (lam < 8) v1t_s[s*8 + lam] = vtmp;
    };

    if (w == 0) {
      const int i0 = lam & 31;
      float c[32], rd = 0.0f;
#pragma unroll
      for (int k = 0; k < 32; ++k) c[k] = uni[i0*33 + k];
#pragma unroll
      for (int j = 0; j < 32; ++j) {
        float dj = __shfl(c[j], j);
        float rinv = rsqrtf(dj);
        if (i0 == j) rd = rinv;
        c[j] *= rinv;
#pragma unroll
        for (int k = j+1; k < 32; ++k) {
          float Lkj = __shfl(c[j], k);
          c[k] = fmaf(-Lkj, c[j], c[k]);
        }
      }
      float acc = rhs32_s[i0];
      float ystore = 0.0f;
#pragma unroll
      for (int k = 0; k < 32; ++k) {          // L y = rhs
        float yk = __shfl(acc, k) * __shfl(rd, k);
        if (i0 == k) ystore = yk;
        acc = fmaf(-c[k], yk, acc);
      }
#pragma unroll
      for (int k = 0; k < 32; ++k) uni[i0*33 + k] = c[k];   // stage L
      float acc2 = ystore;
      float xstore = 0.0f;
#pragma unroll
      for (int m = 31; m >= 0; --m) {          // L^T x = y
        float xm = __shfl(acc2, m) * __shfl(rd, m);
        if (i0 == m) xstore = xm;
        float Lmk = uni[m*33 + i0];
        acc2 = fmaf(-Lmk, xm, acc2);
      }
      if (lam < 32) y32_s[lam] = xstore;
    } else if (w == 1) {
      zprow(0);
      zprow(16);
      const int r1 = lam >> 3, r2 = lam & 7;
      float acc = 0.0f;
#pragma unroll 4
      for (int s = 0; s < 32; ++s)
        acc = fmaf(KM_s[r1*33 + s], KM_s[r2*33 + s], acc);
#pragma unroll 4
      for (int l = 0; l < 64; ++l)
        acc = fmaf(Kt_s[l*8 + r1] * qv_s[l], Kt_s[l*8 + r2], acc);
      C8_s[lam] = acc + (r1 == r2 ? 1.0f : 0.0f);
      chol8M8();
    } else {
      const int base = (w - 2) * 5;
      for (int k = 0; k < 5; ++k) {
        int idx = base + k;
        int s = idx + 1 + (idx >= 15 ? 1 : 0);
        zprow(s);
      }
    }
    __syncthreads();  // B4

    // ---- P5: h, u = Pp_mv(h), m_f ----
    float h_r;
    {
      float acc = 0.0f;
#pragma unroll
      for (int s4 = 0; s4 < 32; s4 += 4) {
        float4 yb = *(const float4*)&y32_s[s4];
        acc = fmaf(Mc_s[lam*33 + s4+0], yb.x, acc);
        acc = fmaf(Mc_s[lam*33 + s4+1], yb.y, acc);
        acc = fmaf(Mc_s[lam*33 + s4+2], yb.z, acc);
        acc = fmaf(Mc_s[lam*33 + s4+3], yb.w, acc);
      }
      h_r = u1 - qi_r*acc + kt_r;
    }
#pragma unroll
    for (int i = 0; i < 4; ++i) {
      float tv = wsum(Mc_s[lam*33 + 4*w + i] * h_r);
      if (lam == 0) th_s[4*w + i] = tv;
    }
    __syncthreads();  // B5
    float u_r;
    {
      float acc = 0.0f;
#pragma unroll
      for (int s4 = 0; s4 < 32; s4 += 4) {
        float4 tb = *(const float4*)&th_s[s4];
        acc = fmaf(Mc_s[lam*33 + s4+0], tb.x, acc);
        acc = fmaf(Mc_s[lam*33 + s4+1], tb.y, acc);
        acc = fmaf(Mc_s[lam*33 + s4+2], tb.z, acc);
        acc = fmaf(Mc_s[lam*33 + s4+3], tb.w, acc);
      }
      u_r = acc + q_r*h_r;
    }
    float t8r[8];
#pragma unroll
    for (int r = 0; r < 8; ++r) t8r[r] = wsum(Kreg[r] * u_r);
    float y8[8];
#pragma unroll
    for (int r1i = 0; r1i < 8; ++r1i) {
      float4 ma = *(const float4*)&M8_s[r1i*8];
      float4 mb = *(const float4*)&M8_s[r1i*8+4];
      y8[r1i] = ma.x*t8r[0]+ma.y*t8r[1]+ma.z*t8r[2]+ma.w*t8r[3]
              + mb.x*t8r[4]+mb.y*t8r[5]+mb.z*t8r[6]+mb.w*t8r[7];
    }
    float gv = 0.0f;
#pragma unroll
    for (int r = 0; r < 8; ++r) gv = fmaf(Kreg[r], y8[r], gv);
#pragma unroll
    for (int i = 0; i < 4; ++i) {
      float tv = wsum(Mc_s[lam*33 + 4*w + i] * gv);
      if (lam == 0) tg_s[4*w + i] = tv;
    }
    __syncthreads();  // B6
    float mf_r;
    {
      float acc = 0.0f;
#pragma unroll
      for (int s4 = 0; s4 < 32; s4 += 4) {
        float4 tb = *(const float4*)&tg_s[s4];
        acc = fmaf(Mc_s[lam*33 + s4+0], tb.x, acc);
        acc = fmaf(Mc_s[lam*33 + s4+1], tb.y, acc);
        acc = fmaf(Mc_s[lam*33 + s4+2], tb.z, acc);
        acc = fmaf(Mc_s[lam*33 + s4+3], tb.w, acc);
      }
      mf_r = u_r - acc - q_r*gv;
    }
    if (w == 0) outp[((size_t)t*B_ + b)*L_ + lam] = mf_r;

    // ---- P6: y1 = M8 v1t (per s), g = K y1 ----
    if (lam < 32) {
      const int i = lam >> 3, r1i = lam & 7;
      const int s = 4*w + i;
      float4 va = *(const float4*)&v1t_s[s*8];
      float4 vb = *(const float4*)&v1t_s[s*8+4];
      float4 ma = *(const float4*)&M8_s[r1i*8];
      float4 mb = *(const float4*)&M8_s[r1i*8+4];
      float yv = ma.x*va.x+ma.y*va.y+ma.z*va.z+ma.w*va.w
               + mb.x*vb.x+mb.y*vb.y+mb.z*vb.z+mb.w*vb.w;
      v1t_s[s*8 + r1i] = yv;
    }
#pragma unroll
    for (int i = 0; i < 4; ++i) {
      const int s = 4*w + i;
      float4 ya = *(const float4*)&v1t_s[s*8];
      float4 yb = *(const float4*)&v1t_s[s*8+4];
      float gg = Kreg[0]*ya.x + Kreg[1]*ya.y + Kreg[2]*ya.z + Kreg[3]*ya.w
               + Kreg[4]*yb.x + Kreg[5]*yb.y + Kreg[6]*yb.z + Kreg[7]*yb.w;
      g_s[s*68 + lam] = gg;
    }
    __syncthreads();  // B7

    // ---- P7: ag = Mc^T g (per s) -> uni stride 36 ----
    {
      const int s2 = lam & 31, hi = lam >> 5;
      const int sa = 4*w + 2*hi, sb = sa + 1;
      float aa = 0, ab = 0;
#pragma unroll 4
      for (int l4 = 0; l4 < 64; l4 += 4) {
        float4 ga4 = *(const float4*)&g_s[sa*68 + l4];
        float4 gb4 = *(const float4*)&g_s[sb*68 + l4];
        float mc0 = Mc_s[(l4+0)*33 + s2];
        float mc1 = Mc_s[(l4+1)*33 + s2];
        float mc2 = Mc_s[(l4+2)*33 + s2];
        float mc3 = Mc_s[(l4+3)*33 + s2];
        aa = fmaf(mc0, ga4.x, aa); aa = fmaf(mc1, ga4.y, aa);
        aa = fmaf(mc2, ga4.z, aa); aa = fmaf(mc3, ga4.w, aa);
        ab = fmaf(mc0, gb4.x, ab); ab = fmaf(mc1, gb4.y, ab);
        ab = fmaf(mc2, gb4.z, ab); ab = fmaf(mc3, gb4.w, ab);
      }
      uni[sa*36 + s2] = aa;
      uni[sb*36 + s2] = ab;
    }
    __syncthreads();  // B8

    // ---- P8: z = m_f + z_p_c - (Mc ag + Q g) ----
#pragma unroll
    for (int i = 0; i < 4; ++i) {
      const int s = 4*w + i;
      float acc = 0.0f;
#pragma unroll
      for (int s4 = 0; s4 < 32; s4 += 4) {
        float4 ab4 = *(const float4*)&uni[s*36 + s4];
        acc = fmaf(Mc_s[lam*33 + s4+0], ab4.x, acc);
        acc = fmaf(Mc_s[lam*33 + s4+1], ab4.y, acc);
        acc = fmaf(Mc_s[lam*33 + s4+2], ab4.z, acc);
        acc = fmaf(Mc_s[lam*33 + s4+3], ab4.w, acc);
      }
      float gg = g_s[s*68 + lam];
      float zp = z_s[s*68 + lam];
      z_s[s*68 + lam] = mf_r + zp - acc - q_r*gg;
    }
    __syncthreads();  // B9
  }
}

extern "C" void kernel_launch(void* const* d_in, const int* in_sizes, int n_in,
                              void* d_out, int out_size, void* d_ws, size_t ws_size,
                              hipStream_t stream) {
  (void)in_sizes; (void)n_in; (void)out_size; (void)d_ws; (void)ws_size;
  nlf_kernel<<<dim3(B_), dim3(512), 0, stream>>>(
      (const float*)d_in[0], (const float*)d_in[1], (const float*)d_in[2],
      (const float*)d_in[3], (const float*)d_in[4], (const float*)d_in[5],
      (const float*)d_in[6], (const float*)d_in[7], (const float*)d_in[8],
      (const float*)d_in[9], (const float*)d_in[10], (float*)d_out);
}

// Round 2
// 15388.948 us; speedup vs baseline: 1.0612x; 1.0612x over previous
//
#include <hip/hip_runtime.h>
#include <cstdint>
#include <cstddef>

namespace {
constexpr int T_ = 500, S_ = 32, B_ = 128, L_ = 64, R_ = 8;

__device__ __forceinline__ float rdlane(float v, int l) {
  return __int_as_float(__builtin_amdgcn_readlane(__float_as_int(v), l));
}
template<int CTRL, int RM>
__device__ __forceinline__ float dppadd(float v) {
  int t = __builtin_amdgcn_update_dpp(0, __float_as_int(v), CTRL, RM, 0xf, false);
  return v + __int_as_float(t);
}
// full 64-lane sum; total lands in lane 63 (VALU-only, no DS)
__device__ __forceinline__ float wredsum(float v) {
  v = dppadd<0x111, 0xf>(v);   // row_shr:1
  v = dppadd<0x112, 0xf>(v);   // row_shr:2
  v = dppadd<0x114, 0xf>(v);   // row_shr:4
  v = dppadd<0x118, 0xf>(v);   // row_shr:8
  v = dppadd<0x142, 0xa>(v);   // row_bcast:15 -> rows 1,3
  v = dppadd<0x143, 0xc>(v);   // row_bcast:31 -> rows 2,3
  return v;
}
__device__ __forceinline__ float wsum(float v) {  // all-lanes result (step0 only)
  v += __shfl_xor(v, 1);  v += __shfl_xor(v, 2);  v += __shfl_xor(v, 4);
  v += __shfl_xor(v, 8);  v += __shfl_xor(v, 16); v += __shfl_xor(v, 32);
  return v;
}
__device__ __forceinline__ void gload16(const float* g, float* l) {
  __builtin_amdgcn_global_load_lds((const __attribute__((address_space(1))) uint32_t*)g,
                                   (__attribute__((address_space(3))) uint32_t*)l,
                                   16, 0, 0);
}
}  // namespace

// One block per batch element b. 512 threads = 8 waves.
__global__ __launch_bounds__(512, 2) void nlf_kernel(
    const float* __restrict__ m0p, const float* __restrict__ q0p,
    const float* __restrict__ qp,  const float* __restrict__ kp,
    const float* __restrict__ Kp,  const float* __restrict__ Ap,
    const float* __restrict__ wp0p, const float* __restrict__ wf0p,
    const float* __restrict__ wp1p, const float* __restrict__ wp2p,
    const float* __restrict__ wfp,  float* __restrict__ outp)
{
  __shared__ __align__(16) float z_s[S_*68];      // carry z' (z - mf) / z_p_c
  __shared__ __align__(16) float g_s[S_*68];      // K@y1 per s
  __shared__ __align__(16) float Mc_s[L_*33];     // M_c[l][s]
  __shared__ __align__(16) float uni[1160];       // mp_part / G+L / ag
  __shared__ __align__(16) float wp1b[2][S_*S_];
  __shared__ __align__(16) float wp2b[2][S_*L_];
  __shared__ __align__(16) float wf_s[S_*R_];
  __shared__ __align__(16) float Kt_s[L_*R_];
  __shared__ __align__(16) float v1t_s[S_*R_];
  __shared__ __align__(16) float KM_s[S_*R_];     // [s*8+r]
  __shared__ __align__(16) float M8_s[64];
  __shared__ __align__(16) float C8_s[64];
  __shared__ __align__(16) float rhs32_s[S_];
  __shared__ __align__(16) float th_s[S_];
  __shared__ __align__(16) float hv_s[L_];
  __shared__ __align__(16) float mf_s[L_];
  __shared__ __align__(16) float qv_s[L_];
  __shared__ __align__(16) float qiv_s[L_];
  __shared__ __align__(16) float q0v_s[L_];

  const int tid = threadIdx.x;
  const int lam = tid & 63;
  const int w   = tid >> 6;
  const int b   = blockIdx.x;

  float Areg[64];
#pragma unroll
  for (int j4 = 0; j4 < 16; ++j4) {
    float4 a4 = *(const float4*)(Ap + (size_t)lam*64 + j4*4);
    Areg[4*j4+0]=a4.x; Areg[4*j4+1]=a4.y; Areg[4*j4+2]=a4.z; Areg[4*j4+3]=a4.w;
  }
  const float q_r  = qp[lam];
  const float qi_r = 1.0f / q_r;
  const float qs_r = sqrtf(q_r);
  const float q0_r = q0p[lam];
  const float m0_r = m0p[lam];
  if (tid < 64) { qv_s[tid] = q_r; qiv_s[tid] = qi_r; q0v_s[tid] = q0_r; }

  float Kreg[8];
  {
    const float* kb = Kp + (size_t)b*(L_*R_) + lam*R_;
    float4 ka = *(const float4*)kb, kb4 = *(const float4*)(kb+4);
    Kreg[0]=ka.x;Kreg[1]=ka.y;Kreg[2]=ka.z;Kreg[3]=ka.w;
    Kreg[4]=kb4.x;Kreg[5]=kb4.y;Kreg[6]=kb4.z;Kreg[7]=kb4.w;
  }
  float kt_r = kp[(size_t)b*L_ + lam];

  // ---- prologue async loads ----
  if (w == 0) {                       // wp1[0] -> wp1b[1]
#pragma unroll
    for (int m = 0; m < 4; ++m) {
      int f = m*256 + lam*4, s = f >> 5, c = f & 31;
      gload16(wp1p + ((size_t)s*B_ + b)*S_ + c, &wp1b[1][f]);
    }
  } else if (w == 1 || w == 2) {      // wp2[0] -> wp2b[1]
#pragma unroll
    for (int m = 0; m < 4; ++m) {
      int f = (w-1)*1024 + m*256 + lam*4, s = f >> 6, c = f & 63;
      gload16(wp2p + ((size_t)s*B_ + b)*L_ + c, &wp2b[1][f]);
    }
  } else if (w == 3) {                // wf0 -> wf_s ; K[0] -> Kt_s
    { int f = lam*4, s = f >> 3, c = f & 7;
      gload16(wf0p + ((size_t)s*B_ + b)*R_ + c, &wf_s[f]); }
#pragma unroll
    for (int m = 0; m < 2; ++m) {
      int f = m*256 + lam*4;
      gload16(Kp + (size_t)b*(L_*R_) + f, &Kt_s[f]);
    }
  } else if (w == 4 || w == 5) {      // w_p0 -> wp2b[0]
#pragma unroll
    for (int m = 0; m < 4; ++m) {
      int f = (w-4)*1024 + m*256 + lam*4, s = f >> 6, c = f & 63;
      gload16(wp0p + ((size_t)s*B_ + b)*L_ + c, &wp2b[0][f]);
    }
  }
  __syncthreads();

  // 8x8 SPD: C8_s -> M8_s = inv(C8) via in-register Cholesky (rows in lanes 0-7)
  auto chol8M8 = [&]() {
    const int i8 = lam & 7;
    float c8[8], rd8 = 0.0f;
#pragma unroll
    for (int k = 0; k < 8; ++k) c8[k] = C8_s[i8*8 + k];
#pragma unroll
    for (int j = 0; j < 8; ++j) {
      float dj = rdlane(c8[j], j);
      float rinv = rsqrtf(dj);
      if (i8 == j) rd8 = rinv;
      c8[j] *= rinv;
#pragma unroll
      for (int k = j+1; k < 8; ++k)
        c8[k] = fmaf(-rdlane(c8[j], k), c8[j], c8[k]);
    }
    float w8[8];                       // lane holds column i8 of W = L^-1
#pragma unroll
    for (int i = 0; i < 8; ++i) {
      float sacc = (i == i8) ? 1.0f : 0.0f;
#pragma unroll
      for (int k = 0; k < i; ++k)
        sacc = fmaf(-rdlane(c8[k], i), w8[k], sacc);
      w8[i] = sacc * rdlane(rd8, i);
    }
#pragma unroll
    for (int i = 0; i < 8; ++i) {      // M8 = W^T W
      float msum = 0.0f;
#pragma unroll
      for (int k = 0; k < 8; ++k)
        msum = fmaf(rdlane(w8[k], i), w8[k], msum);
      if (lam < 8) M8_s[i*8 + lam] = msum;
    }
  };

  // ================= step 0 =================
  {
    const float Pp = q0_r;
    const float h0 = m0_r / Pp + kt_r;
    if (w == 0) {
      const int r1 = lam >> 3, r2 = lam & 7;
      float acc = 0.0f;
#pragma unroll 4
      for (int l = 0; l < 64; ++l)
        acc = fmaf(Kt_s[l*8 + r1] * q0v_s[l], Kt_s[l*8 + r2], acc);
      C8_s[lam] = acc + (r1 == r2 ? 1.0f : 0.0f);
      chol8M8();
      float t8[8];
#pragma unroll
      for (int r = 0; r < 8; ++r) t8[r] = wsum(Pp * Kreg[r] * h0);
      float acc2 = 0.0f;
#pragma unroll
      for (int r1i = 0; r1i < 8; ++r1i) {
        float4 ma = *(const float4*)&M8_s[r1i*8];
        float4 mb = *(const float4*)&M8_s[r1i*8+4];
        float y = ma.x*t8[0]+ma.y*t8[1]+ma.z*t8[2]+ma.w*t8[3]
                + mb.x*t8[4]+mb.y*t8[5]+mb.z*t8[6]+mb.w*t8[7];
        acc2 = fmaf(Kreg[r1i], y, acc2);
      }
      float m0f = Pp*h0 - Pp*acc2;
      mf_s[lam] = m0f;
      outp[(size_t)b*L_ + lam] = m0f;
    }
    __syncthreads();

    const float qs0 = sqrtf(q0_r);
#pragma unroll
    for (int i = 0; i < 4; ++i) {
      const int s = 4*w + i;
      float zp = qs0 * wp2b[0][s*64 + lam];
      float v1[8];
#pragma unroll
      for (int r = 0; r < 8; ++r)
        v1[r] = wsum(Kreg[r] * zp) + wf_s[s*8 + r];
      float acc = 0.0f;
#pragma unroll
      for (int r1i = 0; r1i < 8; ++r1i) {
        float4 ma = *(const float4*)&M8_s[r1i*8];
        float4 mb = *(const float4*)&M8_s[r1i*8+4];
        float y = ma.x*v1[0]+ma.y*v1[1]+ma.z*v1[2]+ma.w*v1[3]
                + mb.x*v1[4]+mb.y*v1[5]+mb.z*v1[6]+mb.w*v1[7];
        acc = fmaf(Kreg[r1i], y, acc);
      }
      z_s[s*68 + lam] = zp - Pp*acc;   // z' excludes m_f (added in next dyn)
    }
  }
  __syncthreads();

  // ================= steps 1..T-1 =================
  for (int t = 1; t < T_; ++t) {
    const int cb = t & 1, nb = cb ^ 1;

    // per-lane K/k reload (VGPR loads; drained by B1, first use in P2)
    {
      const float* kb = Kp + ((size_t)t*B_ + b)*(L_*R_) + lam*R_;
      float4 ka = *(const float4*)kb, kb4 = *(const float4*)(kb+4);
      Kreg[0]=ka.x;Kreg[1]=ka.y;Kreg[2]=ka.z;Kreg[3]=ka.w;
      Kreg[4]=kb4.x;Kreg[5]=kb4.y;Kreg[6]=kb4.z;Kreg[7]=kb4.w;
      kt_r = kp[((size_t)t*B_ + b)*L_ + lam];
    }

    // ---- P1: dyn on z = z' + mf ----
    float dmf = 0.0f;
#pragma unroll
    for (int j4 = 0; j4 < 16; ++j4) {
      float4 m4 = *(const float4*)&mf_s[4*j4];
      dmf = fmaf(m4.x, Areg[4*j4+0], dmf);
      dmf = fmaf(m4.y, Areg[4*j4+1], dmf);
      dmf = fmaf(m4.z, Areg[4*j4+2], dmf);
      dmf = fmaf(m4.w, Areg[4*j4+3], dmf);
    }
    const float mfl = mf_s[lam];
    float zn[4];
#pragma unroll
    for (int i = 0; i < 4; ++i) {
      const int s = 4*w + i;
      float a0=0,a1=0,a2=0,a3=0;
#pragma unroll
      for (int j4 = 0; j4 < 16; ++j4) {
        float4 zb = *(const float4*)&z_s[s*68 + 4*j4];
        a0 = fmaf(zb.x, Areg[4*j4+0], a0);
        a1 = fmaf(zb.y, Areg[4*j4+1], a1);
        a2 = fmaf(zb.z, Areg[4*j4+2], a2);
        a3 = fmaf(zb.w, Areg[4*j4+3], a3);
      }
      float x = ((a0+a1)+(a2+a3)) + dmf;
      float e = __expf(2.0f*x);
      float tnh = 1.0f - 2.0f/(e + 1.0f);
      zn[i] = (z_s[s*68 + lam] + mfl) + 0.1f*tnh;
    }
    uni[w*68 + lam] = zn[0]+zn[1]+zn[2]+zn[3];
    __syncthreads();  // B1

    // ---- P0: async prefetch issued here; drains at B2 under P2 compute ----
    if (w == 0) {
      if (t < T_-1) {
#pragma unroll
        for (int m = 0; m < 4; ++m) {
          int f = m*256 + lam*4, s = f >> 5, c = f & 31;
          gload16(wp1p + (((size_t)t*S_ + s)*B_ + b)*S_ + c, &wp1b[nb][f]);
        }
      }
    } else if (w == 1 || w == 2) {
      if (t < T_-1) {
#pragma unroll
        for (int m = 0; m < 4; ++m) {
          int f = (w-1)*1024 + m*256 + lam*4, s = f >> 6, c = f & 63;
          gload16(wp2p + (((size_t)t*S_ + s)*B_ + b)*L_ + c, &wp2b[nb][f]);
        }
      }
    } else if (w == 3) {
      { int f = lam*4, s = f >> 3, c = f & 7;
        gload16(wfp + (((size_t)(t-1)*S_ + s)*B_ + b)*R_ + c, &wf_s[f]); }
#pragma unroll
      for (int m = 0; m < 2; ++m) {
        int f = m*256 + lam*4;
        gload16(Kp + ((size_t)t*B_ + b)*(L_*R_) + f, &Kt_s[f]);
      }
    }

    // ---- P2: m_p, M_c, rhs32 = Mc^T u1, KM = K^T Mc (DPP reductions) ----
    float mp = 0.0f;
#pragma unroll
    for (int ww = 0; ww < 8; ++ww) mp += uni[ww*68 + lam];
    mp *= 0.03125f;
    const float u1 = qi_r * mp;
    float mcv[4];
#pragma unroll
    for (int i = 0; i < 4; ++i) {
      const int s = 4*w + i;
      mcv[i] = (zn[i] - mp) * 0.17677669529663689f;
      Mc_s[lam*33 + s] = mcv[i];
      float rv = wredsum(mcv[i] * u1);
      float kmv[8];
#pragma unroll
      for (int r = 0; r < 8; ++r) kmv[r] = wredsum(mcv[i] * Kreg[r]);
      if (lam == 63) {
        rhs32_s[s] = rv;
        *(float4*)&KM_s[s*8]   = make_float4(kmv[0],kmv[1],kmv[2],kmv[3]);
        *(float4*)&KM_s[s*8+4] = make_float4(kmv[4],kmv[5],kmv[6],kmv[7]);
      }
    }
    __syncthreads();  // B2

    // ---- P3: G = Mc^T Qi Mc + I -> uni (stride 33) ----
    {
      const int s2 = lam & 31, hi = lam >> 5;
      const int s1a = 4*w + 2*hi, s1b = s1a + 1;
      float ga = 0, gb = 0;
#pragma unroll 4
      for (int l = 0; l < 64; ++l) {
        float mc2 = Mc_s[l*33 + s2];
        float tqm = qiv_s[l] * mc2;
        ga = fmaf(Mc_s[l*33 + s1a], tqm, ga);
        gb = fmaf(Mc_s[l*33 + s1b], tqm, gb);
      }
      if (s1a == s2) ga += 1.0f;
      if (s1b == s2) gb += 1.0f;
      uni[s1a*33 + s2] = ga;
      uni[s1b*33 + s2] = gb;
    }
    __syncthreads();  // B3

    // ---- P4: wave0 = 32x32 chol + fused fwd + back solve;
    //          wave1 = 2 zp rows + C8/chol8/M8; waves2-7 = 5 zp rows ----
    auto zprow = [&](int s) {
      float acc = 0.0f;
#pragma unroll
      for (int p4 = 0; p4 < 32; p4 += 4) {
        float4 wb = *(const float4*)&wp1b[cb][s*32 + p4];
        acc = fmaf(Mc_s[lam*33 + p4+0], wb.x, acc);
        acc = fmaf(Mc_s[lam*33 + p4+1], wb.y, acc);
        acc = fmaf(Mc_s[lam*33 + p4+2], wb.z, acc);
        acc = fmaf(Mc_s[lam*33 + p4+3], wb.w, acc);
      }
      float zp = acc + qs_r * wp2b[cb][s*64 + lam];
      z_s[s*68 + lam] = zp;
      float vv[8];
#pragma unroll
      for (int r = 0; r < 8; ++r) vv[r] = wredsum(Kreg[r] * zp);
      if (lam == 63) {
        float4 wfa = *(const float4*)&wf_s[s*8];
        float4 wfb = *(const float4*)&wf_s[s*8+4];
        *(float4*)&v1t_s[s*8]   = make_float4(vv[0]+wfa.x, vv[1]+wfa.y,
                                              vv[2]+wfa.z, vv[3]+wfa.w);
        *(float4*)&v1t_s[s*8+4] = make_float4(vv[4]+wfb.x, vv[5]+wfb.y,
                                              vv[6]+wfb.z, vv[7]+wfb.w);
      }
    };

    float xstore = 0.0f;   // wave0: y32[i0]
    if (w == 0) {
      const int i0 = lam & 31;
      float c[32];
#pragma unroll
      for (int k = 0; k < 32; ++k) c[k] = uni[i0*33 + k];
      float acc = rhs32_s[i0];
      float rdv = 0.0f, yacc = 0.0f;
#pragma unroll
      for (int j = 0; j < 32; ++j) {
        float dj = rdlane(c[j], j);
        float rinv = rsqrtf(dj);
        if (i0 == j) rdv = rinv;
        c[j] *= rinv;
        uni[i0*33 + j] = c[j];                 // stage L for backsolve
        float yj = rdlane(acc, j) * rinv;      // fused forward solve
        if (i0 == j) yacc = yj;
        acc = fmaf(-c[j], yj, acc);
#pragma unroll
        for (int k = j+1; k < 32; ++k)
          c[k] = fmaf(-rdlane(c[j], k), c[j], c[k]);
      }
      float acc2 = yacc;                        // backward solve L^T x = y
#pragma unroll
      for (int m = 31; m >= 0; --m) {
        float xm = rdlane(acc2, m) * rdlane(rdv, m);
        if (i0 == m) xstore = xm;
        acc2 = fmaf(-uni[m*33 + i0], xm, acc2);
      }
    } else if (w == 1) {
      zprow(0);
      zprow(16);
      const int r1 = lam >> 3, r2 = lam & 7;
      float acc = 0.0f;
#pragma unroll 4
      for (int s = 0; s < 32; ++s)
        acc = fmaf(KM_s[s*8 + r1], KM_s[s*8 + r2], acc);
#pragma unroll 4
      for (int l = 0; l < 64; ++l)
        acc = fmaf(Kt_s[l*8 + r1] * qv_s[l], Kt_s[l*8 + r2], acc);
      C8_s[lam] = acc + (r1 == r2 ? 1.0f : 0.0f);
      chol8M8();
    } else {
      const int base = (w - 2) * 5;
      const int st = base + ((base >= 15) ? 2 : 1);
      zprow(st); zprow(st+1); zprow(st+2); zprow(st+3); zprow(st+4);
    }
    __syncthreads();  // B4

    // ---- P5 split: wave0 = m_f chain; waves1-7 = z-update rows ----
    if (w == 0) {
      // h = u1 - Qi*(Mc y32) + k_t
      float mcdot = 0.0f;
#pragma unroll
      for (int s = 0; s < 32; ++s)
        mcdot = fmaf(Mc_s[lam*33 + s], rdlane(xstore, s), mcdot);
      const float h_r = u1 - qi_r*mcdot + kt_r;
      hv_s[lam] = h_r;
      // th = Mc^T h (transpose loop, duplicated halves)
      const int s2w = lam & 31;
      float thv = 0.0f;
#pragma unroll
      for (int l = 0; l < 64; l += 4) {
        float4 hb = *(const float4*)&hv_s[l];
        thv = fmaf(Mc_s[(l+0)*33 + s2w], hb.x, thv);
        thv = fmaf(Mc_s[(l+1)*33 + s2w], hb.y, thv);
        thv = fmaf(Mc_s[(l+2)*33 + s2w], hb.z, thv);
        thv = fmaf(Mc_s[(l+3)*33 + s2w], hb.w, thv);
      }
      if (lam < 32) th_s[lam] = thv;
      // u = Mc th + q h
      float mcth = 0.0f;
#pragma unroll
      for (int s4 = 0; s4 < 32; s4 += 4) {
        float4 tb = *(const float4*)&th_s[s4];
        mcth = fmaf(Mc_s[lam*33 + s4+0], tb.x, mcth);
        mcth = fmaf(Mc_s[lam*33 + s4+1], tb.y, mcth);
        mcth = fmaf(Mc_s[lam*33 + s4+2], tb.z, mcth);
        mcth = fmaf(Mc_s[lam*33 + s4+3], tb.w, mcth);
      }
      const float u_r = mcth + q_r*h_r;
      // t8 = K^T u
      float t8s[8];
#pragma unroll
      for (int r = 0; r < 8; ++r) {
        float v = wredsum(Kreg[r] * u_r);
        t8s[r] = rdlane(v, 63);
      }
      // y8 = M8 t8 ; gv = K y8
      float gvv = 0.0f;
#pragma unroll
      for (int r1i = 0; r1i < 8; ++r1i) {
        float4 ma = *(const float4*)&M8_s[r1i*8];
        float4 mb = *(const float4*)&M8_s[r1i*8+4];
        float y = ma.x*t8s[0]+ma.y*t8s[1]+ma.z*t8s[2]+ma.w*t8s[3]
                + mb.x*t8s[4]+mb.y*t8s[5]+mb.z*t8s[6]+mb.w*t8s[7];
        gvv = fmaf(Kreg[r1i], y, gvv);
      }
      hv_s[lam] = gvv;
      // tg = Mc^T gv
      float tgv = 0.0f;
#pragma unroll
      for (int l = 0; l < 64; l += 4) {
        float4 gb = *(const float4*)&hv_s[l];
        tgv = fmaf(Mc_s[(l+0)*33 + s2w], gb.x, tgv);
        tgv = fmaf(Mc_s[(l+1)*33 + s2w], gb.y, tgv);
        tgv = fmaf(Mc_s[(l+2)*33 + s2w], gb.z, tgv);
        tgv = fmaf(Mc_s[(l+3)*33 + s2w], gb.w, tgv);
      }
      if (lam < 32) th_s[lam] = tgv;
      // mf = u - Mc tg - q gv
      float mctg = 0.0f;
#pragma unroll
      for (int s4 = 0; s4 < 32; s4 += 4) {
        float4 tb = *(const float4*)&th_s[s4];
        mctg = fmaf(Mc_s[lam*33 + s4+0], tb.x, mctg);
        mctg = fmaf(Mc_s[lam*33 + s4+1], tb.y, mctg);
        mctg = fmaf(Mc_s[lam*33 + s4+2], tb.z, mctg);
        mctg = fmaf(Mc_s[lam*33 + s4+3], tb.w, mctg);
      }
      const float mf_r = u_r - mctg - q_r*gvv;
      mf_s[lam] = mf_r;
      outp[((size_t)t*B_ + b)*L_ + lam] = mf_r;
    } else {
      auto rowY1G = [&](int s) {
        float4 va = *(const float4*)&v1t_s[s*8];
        float4 vb = *(const float4*)&v1t_s[s*8+4];
        float gg = 0.0f;
#pragma unroll
        for (int r1i = 0; r1i < 8; ++r1i) {
          float4 ma = *(const float4*)&M8_s[r1i*8];
          float4 mb = *(const float4*)&M8_s[r1i*8+4];
          float y = ma.x*va.x+ma.y*va.y+ma.z*va.z+ma.w*va.w
                  + mb.x*vb.x+mb.y*vb.y+mb.z*vb.z+mb.w*vb.w;
          gg = fmaf(Kreg[r1i], y, gg);
        }
        g_s[s*68 + lam] = gg;
      };
      auto pairAG = [&](int sa, int sb) {
        const int s2 = lam & 31;
        const int sr = (lam >= 32) ? sb : sa;
        float aa = 0.0f;
#pragma unroll
        for (int l4 = 0; l4 < 64; l4 += 4) {
          float4 g4 = *(const float4*)&g_s[sr*68 + l4];
          aa = fmaf(Mc_s[(l4+0)*33 + s2], g4.x, aa);
          aa = fmaf(Mc_s[(l4+1)*33 + s2], g4.y, aa);
          aa = fmaf(Mc_s[(l4+2)*33 + s2], g4.z, aa);
          aa = fmaf(Mc_s[(l4+3)*33 + s2], g4.w, aa);
        }
        uni[sr*36 + s2] = aa;
      };
      auto rowZ = [&](int s) {
        float acc = 0.0f;
#pragma unroll
        for (int s4 = 0; s4 < 32; s4 += 4) {
          float4 a4 = *(const float4*)&uni[s*36 + s4];
          acc = fmaf(Mc_s[lam*33 + s4+0], a4.x, acc);
          acc = fmaf(Mc_s[lam*33 + s4+1], a4.y, acc);
          acc = fmaf(Mc_s[lam*33 + s4+2], a4.z, acc);
          acc = fmaf(Mc_s[lam*33 + s4+3], a4.w, acc);
        }
        float gg = g_s[s*68 + lam];
        z_s[s*68 + lam] = z_s[s*68 + lam] - acc - q_r*gg;  // z' (mf added next dyn)
      };
      if (w == 1) {
        rowY1G(0); rowY1G(16);
        pairAG(0, 16);
        rowZ(0); rowZ(16);
      } else {
        const int base = (w - 2) * 5;
        const int st = base + ((base >= 15) ? 2 : 1);
        rowY1G(st); rowY1G(st+1); rowY1G(st+2); rowY1G(st+3); rowY1G(st+4);
        pairAG(st, st+1); pairAG(st+2, st+3); pairAG(st+4, st+4);
        rowZ(st); rowZ(st+1); rowZ(st+2); rowZ(st+3); rowZ(st+4);
      }
    }
    __syncthreads();  // B5
  }
}

extern "C" void kernel_launch(void* const* d_in, const int* in_sizes, int n_in,
                              void* d_out, int out_size, void* d_ws, size_t ws_size,
                              hipStream_t stream) {
  (void)in_sizes; (void)n_in; (void)out_size; (void)d_ws; (void)ws_size;
  nlf_kernel<<<dim3(B_), dim3(512), 0, stream>>>(
      (const float*)d_in[0], (const float*)d_in[1], (const float*)d_in[2],
      (const float*)d_in[3], (const float*)d_in[4], (const float*)d_in[5],
      (const float*)d_in[6], (const float*)d_in[7], (const float*)d_in[8],
      (const float*)d_in[9], (const float*)d_in[10], (float*)d_out);
}

// Round 3
// 15374.937 us; speedup vs baseline: 1.0621x; 1.0009x over previous
//
#include <hip/hip_runtime.h>
#include <cstdint>
#include <cstddef>

namespace {
constexpr int T_ = 500, S_ = 32, B_ = 128, L_ = 64, R_ = 8;

__device__ __forceinline__ float rdlane(float v, int l) {
  return __int_as_float(__builtin_amdgcn_readlane(__float_as_int(v), l));
}
template<int CTRL, int RM>
__device__ __forceinline__ float dppadd(float v) {
  int t = __builtin_amdgcn_update_dpp(0, __float_as_int(v), CTRL, RM, 0xf, false);
  return v + __int_as_float(t);
}
// full 64-lane sum; total lands in lane 63 (VALU-only, no DS)
__device__ __forceinline__ float wredsum(float v) {
  v = dppadd<0x111, 0xf>(v);   // row_shr:1
  v = dppadd<0x112, 0xf>(v);   // row_shr:2
  v = dppadd<0x114, 0xf>(v);   // row_shr:4
  v = dppadd<0x118, 0xf>(v);   // row_shr:8
  v = dppadd<0x142, 0xa>(v);   // row_bcast:15 -> rows 1,3
  v = dppadd<0x143, 0xc>(v);   // row_bcast:31 -> rows 2,3
  return v;
}
__device__ __forceinline__ float wsum(float v) {  // all-lanes result (step0 only)
  v += __shfl_xor(v, 1);  v += __shfl_xor(v, 2);  v += __shfl_xor(v, 4);
  v += __shfl_xor(v, 8);  v += __shfl_xor(v, 16); v += __shfl_xor(v, 32);
  return v;
}
__device__ __forceinline__ void gload16(const float* g, float* l) {
  __builtin_amdgcn_global_load_lds((const __attribute__((address_space(1))) uint32_t*)g,
                                   (__attribute__((address_space(3))) uint32_t*)l,
                                   16, 0, 0);
}
}  // namespace

// One block per batch element b. 512 threads = 8 waves.
// launch_bounds(512,1): only one block/CU needed (128 blocks over 256 CUs);
// lifting min-waves from 2 to 1 raises the VGPR cap 128 -> 256 (no spills).
__global__ __launch_bounds__(512, 1) void nlf_kernel(
    const float* __restrict__ m0p, const float* __restrict__ q0p,
    const float* __restrict__ qp,  const float* __restrict__ kp,
    const float* __restrict__ Kp,  const float* __restrict__ Ap,
    const float* __restrict__ wp0p, const float* __restrict__ wf0p,
    const float* __restrict__ wp1p, const float* __restrict__ wp2p,
    const float* __restrict__ wfp,  float* __restrict__ outp)
{
  __shared__ __align__(16) float z_s[S_*68];      // carry z' (z - mf) / z_p_c
  __shared__ __align__(16) float g_s[S_*68];      // K@y1 per s
  __shared__ __align__(16) float Mc_s[L_*33];     // M_c[l][s]
  __shared__ __align__(16) float uni[1160];       // mp_part / G+L / ag
  __shared__ __align__(16) float wp1b[2][S_*S_];
  __shared__ __align__(16) float wp2b[2][S_*L_];
  __shared__ __align__(16) float wf_s[S_*R_];
  __shared__ __align__(16) float Kt_s[L_*R_];
  __shared__ __align__(16) float v1t_s[S_*R_];
  __shared__ __align__(16) float KM_s[S_*R_];     // [s*8+r]
  __shared__ __align__(16) float M8_s[64];
  __shared__ __align__(16) float C8_s[64];
  __shared__ __align__(16) float rhs32_s[S_];
  __shared__ __align__(16) float th_s[S_];
  __shared__ __align__(16) float hv_s[L_];
  __shared__ __align__(16) float mf_s[L_];
  __shared__ __align__(16) float qv_s[L_];
  __shared__ __align__(16) float qiv_s[L_];
  __shared__ __align__(16) float q0v_s[L_];

  const int tid = threadIdx.x;
  const int lam = tid & 63;
  const int w   = tid >> 6;
  const int b   = blockIdx.x;

  float Areg[64];
#pragma unroll
  for (int j4 = 0; j4 < 16; ++j4) {
    float4 a4 = *(const float4*)(Ap + (size_t)lam*64 + j4*4);
    Areg[4*j4+0]=a4.x; Areg[4*j4+1]=a4.y; Areg[4*j4+2]=a4.z; Areg[4*j4+3]=a4.w;
  }
  const float q_r  = qp[lam];
  const float qi_r = 1.0f / q_r;
  const float qs_r = sqrtf(q_r);
  const float q0_r = q0p[lam];
  const float m0_r = m0p[lam];
  if (tid < 64) { qv_s[tid] = q_r; qiv_s[tid] = qi_r; q0v_s[tid] = q0_r; }

  float Kreg[8];
  {
    const float* kb = Kp + (size_t)b*(L_*R_) + lam*R_;
    float4 ka = *(const float4*)kb, kb4 = *(const float4*)(kb+4);
    Kreg[0]=ka.x;Kreg[1]=ka.y;Kreg[2]=ka.z;Kreg[3]=ka.w;
    Kreg[4]=kb4.x;Kreg[5]=kb4.y;Kreg[6]=kb4.z;Kreg[7]=kb4.w;
  }
  float kt_r = kp[(size_t)b*L_ + lam];

  // ---- prologue async loads ----
  if (w == 0) {                       // wp1[0] -> wp1b[1]
#pragma unroll
    for (int m = 0; m < 4; ++m) {
      int f = m*256 + lam*4, s = f >> 5, c = f & 31;
      gload16(wp1p + ((size_t)s*B_ + b)*S_ + c, &wp1b[1][f]);
    }
  } else if (w == 1 || w == 2) {      // wp2[0] -> wp2b[1]
#pragma unroll
    for (int m = 0; m < 4; ++m) {
      int f = (w-1)*1024 + m*256 + lam*4, s = f >> 6, c = f & 63;
      gload16(wp2p + ((size_t)s*B_ + b)*L_ + c, &wp2b[1][f]);
    }
  } else if (w == 3) {                // wf0 -> wf_s ; K[0] -> Kt_s
    { int f = lam*4, s = f >> 3, c = f & 7;
      gload16(wf0p + ((size_t)s*B_ + b)*R_ + c, &wf_s[f]); }
#pragma unroll
    for (int m = 0; m < 2; ++m) {
      int f = m*256 + lam*4;
      gload16(Kp + (size_t)b*(L_*R_) + f, &Kt_s[f]);
    }
  } else if (w == 4 || w == 5) {      // w_p0 -> wp2b[0]
#pragma unroll
    for (int m = 0; m < 4; ++m) {
      int f = (w-4)*1024 + m*256 + lam*4, s = f >> 6, c = f & 63;
      gload16(wp0p + ((size_t)s*B_ + b)*L_ + c, &wp2b[0][f]);
    }
  }
  __syncthreads();

  // 8x8 SPD: C8_s -> M8_s = inv(C8) via in-register Cholesky (rows in lanes 0-7)
  auto chol8M8 = [&]() {
    const int i8 = lam & 7;
    float c8[8], rd8 = 0.0f;
#pragma unroll
    for (int k = 0; k < 8; ++k) c8[k] = C8_s[i8*8 + k];
#pragma unroll
    for (int j = 0; j < 8; ++j) {
      float dj = rdlane(c8[j], j);
      float rinv = rsqrtf(dj);
      if (i8 == j) rd8 = rinv;
      c8[j] *= rinv;
#pragma unroll
      for (int k = j+1; k < 8; ++k)
        c8[k] = fmaf(-rdlane(c8[j], k), c8[j], c8[k]);
    }
    float w8[8];                       // lane holds column i8 of W = L^-1
#pragma unroll
    for (int i = 0; i < 8; ++i) {
      float sacc = (i == i8) ? 1.0f : 0.0f;
#pragma unroll
      for (int k = 0; k < i; ++k)
        sacc = fmaf(-rdlane(c8[k], i), w8[k], sacc);
      w8[i] = sacc * rdlane(rd8, i);
    }
#pragma unroll
    for (int i = 0; i < 8; ++i) {      // M8 = W^T W
      float msum = 0.0f;
#pragma unroll
      for (int k = 0; k < 8; ++k)
        msum = fmaf(rdlane(w8[k], i), w8[k], msum);
      if (lam < 8) M8_s[i*8 + lam] = msum;
    }
  };

  // ================= step 0 =================
  {
    const float Pp = q0_r;
    const float h0 = m0_r / Pp + kt_r;
    if (w == 0) {
      const int r1 = lam >> 3, r2 = lam & 7;
      float acc = 0.0f;
#pragma unroll 4
      for (int l = 0; l < 64; ++l)
        acc = fmaf(Kt_s[l*8 + r1] * q0v_s[l], Kt_s[l*8 + r2], acc);
      C8_s[lam] = acc + (r1 == r2 ? 1.0f : 0.0f);
      chol8M8();
      float t8[8];
#pragma unroll
      for (int r = 0; r < 8; ++r) t8[r] = wsum(Pp * Kreg[r] * h0);
      float acc2 = 0.0f;
#pragma unroll
      for (int r1i = 0; r1i < 8; ++r1i) {
        float4 ma = *(const float4*)&M8_s[r1i*8];
        float4 mb = *(const float4*)&M8_s[r1i*8+4];
        float y = ma.x*t8[0]+ma.y*t8[1]+ma.z*t8[2]+ma.w*t8[3]
                + mb.x*t8[4]+mb.y*t8[5]+mb.z*t8[6]+mb.w*t8[7];
        acc2 = fmaf(Kreg[r1i], y, acc2);
      }
      float m0f = Pp*h0 - Pp*acc2;
      mf_s[lam] = m0f;
      outp[(size_t)b*L_ + lam] = m0f;
    }
    __syncthreads();

    const float qs0 = sqrtf(q0_r);
#pragma unroll
    for (int i = 0; i < 4; ++i) {
      const int s = 4*w + i;
      float zp = qs0 * wp2b[0][s*64 + lam];
      float v1[8];
#pragma unroll
      for (int r = 0; r < 8; ++r)
        v1[r] = wsum(Kreg[r] * zp) + wf_s[s*8 + r];
      float acc = 0.0f;
#pragma unroll
      for (int r1i = 0; r1i < 8; ++r1i) {
        float4 ma = *(const float4*)&M8_s[r1i*8];
        float4 mb = *(const float4*)&M8_s[r1i*8+4];
        float y = ma.x*v1[0]+ma.y*v1[1]+ma.z*v1[2]+ma.w*v1[3]
                + mb.x*v1[4]+mb.y*v1[5]+mb.z*v1[6]+mb.w*v1[7];
        acc = fmaf(Kreg[r1i], y, acc);
      }
      z_s[s*68 + lam] = zp - Pp*acc;   // z' excludes m_f (added in next dyn)
    }
  }
  __syncthreads();

  // ================= steps 1..T-1 =================
  for (int t = 1; t < T_; ++t) {
    const int cb = t & 1, nb = cb ^ 1;

    // per-lane K/k reload (VGPR loads; drained by B1, first use in P2)
    {
      const float* kb = Kp + ((size_t)t*B_ + b)*(L_*R_) + lam*R_;
      float4 ka = *(const float4*)kb, kb4 = *(const float4*)(kb+4);
      Kreg[0]=ka.x;Kreg[1]=ka.y;Kreg[2]=ka.z;Kreg[3]=ka.w;
      Kreg[4]=kb4.x;Kreg[5]=kb4.y;Kreg[6]=kb4.z;Kreg[7]=kb4.w;
      kt_r = kp[((size_t)t*B_ + b)*L_ + lam];
    }

    // ---- P1: dyn on z = z' + mf ----
    float dmf = 0.0f;
#pragma unroll
    for (int j4 = 0; j4 < 16; ++j4) {
      float4 m4 = *(const float4*)&mf_s[4*j4];
      dmf = fmaf(m4.x, Areg[4*j4+0], dmf);
      dmf = fmaf(m4.y, Areg[4*j4+1], dmf);
      dmf = fmaf(m4.z, Areg[4*j4+2], dmf);
      dmf = fmaf(m4.w, Areg[4*j4+3], dmf);
    }
    const float mfl = mf_s[lam];
    float zn[4];
#pragma unroll
    for (int i = 0; i < 4; ++i) {
      const int s = 4*w + i;
      float a0=0,a1=0,a2=0,a3=0;
#pragma unroll
      for (int j4 = 0; j4 < 16; ++j4) {
        float4 zb = *(const float4*)&z_s[s*68 + 4*j4];
        a0 = fmaf(zb.x, Areg[4*j4+0], a0);
        a1 = fmaf(zb.y, Areg[4*j4+1], a1);
        a2 = fmaf(zb.z, Areg[4*j4+2], a2);
        a3 = fmaf(zb.w, Areg[4*j4+3], a3);
      }
      float x = ((a0+a1)+(a2+a3)) + dmf;
      float e = __expf(2.0f*x);
      float tnh = 1.0f - 2.0f/(e + 1.0f);
      zn[i] = (z_s[s*68 + lam] + mfl) + 0.1f*tnh;
    }
    uni[w*68 + lam] = zn[0]+zn[1]+zn[2]+zn[3];
    __syncthreads();  // B1

    // ---- P0: async prefetch issued here; drains at B2 under P2 compute ----
    if (w == 0) {
      if (t < T_-1) {
#pragma unroll
        for (int m = 0; m < 4; ++m) {
          int f = m*256 + lam*4, s = f >> 5, c = f & 31;
          gload16(wp1p + (((size_t)t*S_ + s)*B_ + b)*S_ + c, &wp1b[nb][f]);
        }
      }
    } else if (w == 1 || w == 2) {
      if (t < T_-1) {
#pragma unroll
        for (int m = 0; m < 4; ++m) {
          int f = (w-1)*1024 + m*256 + lam*4, s = f >> 6, c = f & 63;
          gload16(wp2p + (((size_t)t*S_ + s)*B_ + b)*L_ + c, &wp2b[nb][f]);
        }
      }
    } else if (w == 3) {
      { int f = lam*4, s = f >> 3, c = f & 7;
        gload16(wfp + (((size_t)(t-1)*S_ + s)*B_ + b)*R_ + c, &wf_s[f]); }
#pragma unroll
      for (int m = 0; m < 2; ++m) {
        int f = m*256 + lam*4;
        gload16(Kp + ((size_t)t*B_ + b)*(L_*R_) + f, &Kt_s[f]);
      }
    }

    // ---- P2: m_p, M_c, rhs32 = Mc^T u1, KM = K^T Mc (DPP reductions) ----
    float mp = 0.0f;
#pragma unroll
    for (int ww = 0; ww < 8; ++ww) mp += uni[ww*68 + lam];
    mp *= 0.03125f;
    const float u1 = qi_r * mp;
    float mcv[4];
#pragma unroll
    for (int i = 0; i < 4; ++i) {
      const int s = 4*w + i;
      mcv[i] = (zn[i] - mp) * 0.17677669529663689f;
      Mc_s[lam*33 + s] = mcv[i];
      float rv = wredsum(mcv[i] * u1);
      float kmv[8];
#pragma unroll
      for (int r = 0; r < 8; ++r) kmv[r] = wredsum(mcv[i] * Kreg[r]);
      if (lam == 63) {
        rhs32_s[s] = rv;
        *(float4*)&KM_s[s*8]   = make_float4(kmv[0],kmv[1],kmv[2],kmv[3]);
        *(float4*)&KM_s[s*8+4] = make_float4(kmv[4],kmv[5],kmv[6],kmv[7]);
      }
    }
    __syncthreads();  // B2

    // ---- P3: G = Mc^T Qi Mc + I -> uni (stride 33) ----
    {
      const int s2 = lam & 31, hi = lam >> 5;
      const int s1a = 4*w + 2*hi, s1b = s1a + 1;
      float ga = 0, gb = 0;
#pragma unroll 4
      for (int l = 0; l < 64; ++l) {
        float mc2 = Mc_s[l*33 + s2];
        float tqm = qiv_s[l] * mc2;
        ga = fmaf(Mc_s[l*33 + s1a], tqm, ga);
        gb = fmaf(Mc_s[l*33 + s1b], tqm, gb);
      }
      if (s1a == s2) ga += 1.0f;
      if (s1b == s2) gb += 1.0f;
      uni[s1a*33 + s2] = ga;
      uni[s1b*33 + s2] = gb;
    }
    __syncthreads();  // B3

    // ---- P4: wave0 = 32x32 chol + fused fwd + back solve;
    //          wave1 = 2 zp rows + C8/chol8/M8; waves2-7 = 5 zp rows ----
    auto zprow = [&](int s) {
      float acc = 0.0f;
#pragma unroll
      for (int p4 = 0; p4 < 32; p4 += 4) {
        float4 wb = *(const float4*)&wp1b[cb][s*32 + p4];
        acc = fmaf(Mc_s[lam*33 + p4+0], wb.x, acc);
        acc = fmaf(Mc_s[lam*33 + p4+1], wb.y, acc);
        acc = fmaf(Mc_s[lam*33 + p4+2], wb.z, acc);
        acc = fmaf(Mc_s[lam*33 + p4+3], wb.w, acc);
      }
      float zp = acc + qs_r * wp2b[cb][s*64 + lam];
      z_s[s*68 + lam] = zp;
      float vv[8];
#pragma unroll
      for (int r = 0; r < 8; ++r) vv[r] = wredsum(Kreg[r] * zp);
      if (lam == 63) {
        float4 wfa = *(const float4*)&wf_s[s*8];
        float4 wfb = *(const float4*)&wf_s[s*8+4];
        *(float4*)&v1t_s[s*8]   = make_float4(vv[0]+wfa.x, vv[1]+wfa.y,
                                              vv[2]+wfa.z, vv[3]+wfa.w);
        *(float4*)&v1t_s[s*8+4] = make_float4(vv[4]+wfb.x, vv[5]+wfb.y,
                                              vv[6]+wfb.z, vv[7]+wfb.w);
      }
    };

    float xstore = 0.0f;   // wave0: y32[i0]
    if (w == 0) {
      const int i0 = lam & 31;
      float c[32];
#pragma unroll
      for (int k = 0; k < 32; ++k) c[k] = uni[i0*33 + k];
      float acc = rhs32_s[i0];
      float rdv = 0.0f, yacc = 0.0f;
#pragma unroll
      for (int j = 0; j < 32; ++j) {
        float dj = rdlane(c[j], j);
        float rinv = rsqrtf(dj);
        if (i0 == j) rdv = rinv;
        c[j] *= rinv;
        uni[i0*33 + j] = c[j];                 // stage L for backsolve
        float yj = rdlane(acc, j) * rinv;      // fused forward solve
        if (i0 == j) yacc = yj;
        acc = fmaf(-c[j], yj, acc);
#pragma unroll
        for (int k = j+1; k < 32; ++k)
          c[k] = fmaf(-rdlane(c[j], k), c[j], c[k]);
      }
      float acc2 = yacc;                        // backward solve L^T x = y
#pragma unroll
      for (int m = 31; m >= 0; --m) {
        float xm = rdlane(acc2, m) * rdlane(rdv, m);
        if (i0 == m) xstore = xm;
        acc2 = fmaf(-uni[m*33 + i0], xm, acc2);
      }
    } else if (w == 1) {
      zprow(0);
      zprow(16);
      const int r1 = lam >> 3, r2 = lam & 7;
      float acc = 0.0f;
#pragma unroll 4
      for (int s = 0; s < 32; ++s)
        acc = fmaf(KM_s[s*8 + r1], KM_s[s*8 + r2], acc);
#pragma unroll 4
      for (int l = 0; l < 64; ++l)
        acc = fmaf(Kt_s[l*8 + r1] * qv_s[l], Kt_s[l*8 + r2], acc);
      C8_s[lam] = acc + (r1 == r2 ? 1.0f : 0.0f);
      chol8M8();
    } else {
      const int base = (w - 2) * 5;
      const int st = base + ((base >= 15) ? 2 : 1);
      zprow(st); zprow(st+1); zprow(st+2); zprow(st+3); zprow(st+4);
    }
    __syncthreads();  // B4

    // ---- P5 split: wave0 = m_f chain; waves1-7 = z-update rows ----
    if (w == 0) {
      // h = u1 - Qi*(Mc y32) + k_t
      float mcdot = 0.0f;
#pragma unroll
      for (int s = 0; s < 32; ++s)
        mcdot = fmaf(Mc_s[lam*33 + s], rdlane(xstore, s), mcdot);
      const float h_r = u1 - qi_r*mcdot + kt_r;
      hv_s[lam] = h_r;
      // th = Mc^T h (transpose loop, duplicated halves)
      const int s2w = lam & 31;
      float thv = 0.0f;
#pragma unroll
      for (int l = 0; l < 64; l += 4) {
        float4 hb = *(const float4*)&hv_s[l];
        thv = fmaf(Mc_s[(l+0)*33 + s2w], hb.x, thv);
        thv = fmaf(Mc_s[(l+1)*33 + s2w], hb.y, thv);
        thv = fmaf(Mc_s[(l+2)*33 + s2w], hb.z, thv);
        thv = fmaf(Mc_s[(l+3)*33 + s2w], hb.w, thv);
      }
      if (lam < 32) th_s[lam] = thv;
      // u = Mc th + q h
      float mcth = 0.0f;
#pragma unroll
      for (int s4 = 0; s4 < 32; s4 += 4) {
        float4 tb = *(const float4*)&th_s[s4];
        mcth = fmaf(Mc_s[lam*33 + s4+0], tb.x, mcth);
        mcth = fmaf(Mc_s[lam*33 + s4+1], tb.y, mcth);
        mcth = fmaf(Mc_s[lam*33 + s4+2], tb.z, mcth);
        mcth = fmaf(Mc_s[lam*33 + s4+3], tb.w, mcth);
      }
      const float u_r = mcth + q_r*h_r;
      // t8 = K^T u
      float t8s[8];
#pragma unroll
      for (int r = 0; r < 8; ++r) {
        float v = wredsum(Kreg[r] * u_r);
        t8s[r] = rdlane(v, 63);
      }
      // y8 = M8 t8 ; gv = K y8
      float gvv = 0.0f;
#pragma unroll
      for (int r1i = 0; r1i < 8; ++r1i) {
        float4 ma = *(const float4*)&M8_s[r1i*8];
        float4 mb = *(const float4*)&M8_s[r1i*8+4];
        float y = ma.x*t8s[0]+ma.y*t8s[1]+ma.z*t8s[2]+ma.w*t8s[3]
                + mb.x*t8s[4]+mb.y*t8s[5]+mb.z*t8s[6]+mb.w*t8s[7];
        gvv = fmaf(Kreg[r1i], y, gvv);
      }
      hv_s[lam] = gvv;
      // tg = Mc^T gv
      float tgv = 0.0f;
#pragma unroll
      for (int l = 0; l < 64; l += 4) {
        float4 gb = *(const float4*)&hv_s[l];
        tgv = fmaf(Mc_s[(l+0)*33 + s2w], gb.x, tgv);
        tgv = fmaf(Mc_s[(l+1)*33 + s2w], gb.y, tgv);
        tgv = fmaf(Mc_s[(l+2)*33 + s2w], gb.z, tgv);
        tgv = fmaf(Mc_s[(l+3)*33 + s2w], gb.w, tgv);
      }
      if (lam < 32) th_s[lam] = tgv;
      // mf = u - Mc tg - q gv
      float mctg = 0.0f;
#pragma unroll
      for (int s4 = 0; s4 < 32; s4 += 4) {
        float4 tb = *(const float4*)&th_s[s4];
        mctg = fmaf(Mc_s[lam*33 + s4+0], tb.x, mctg);
        mctg = fmaf(Mc_s[lam*33 + s4+1], tb.y, mctg);
        mctg = fmaf(Mc_s[lam*33 + s4+2], tb.z, mctg);
        mctg = fmaf(Mc_s[lam*33 + s4+3], tb.w, mctg);
      }
      const float mf_r = u_r - mctg - q_r*gvv;
      mf_s[lam] = mf_r;
      outp[((size_t)t*B_ + b)*L_ + lam] = mf_r;
    } else {
      auto rowY1G = [&](int s) {
        float4 va = *(const float4*)&v1t_s[s*8];
        float4 vb = *(const float4*)&v1t_s[s*8+4];
        float gg = 0.0f;
#pragma unroll
        for (int r1i = 0; r1i < 8; ++r1i) {
          float4 ma = *(const float4*)&M8_s[r1i*8];
          float4 mb = *(const float4*)&M8_s[r1i*8+4];
          float y = ma.x*va.x+ma.y*va.y+ma.z*va.z+ma.w*va.w
                  + mb.x*vb.x+mb.y*vb.y+mb.z*vb.z+mb.w*vb.w;
          gg = fmaf(Kreg[r1i], y, gg);
        }
        g_s[s*68 + lam] = gg;
      };
      auto pairAG = [&](int sa, int sb) {
        const int s2 = lam & 31;
        const int sr = (lam >= 32) ? sb : sa;
        float aa = 0.0f;
#pragma unroll
        for (int l4 = 0; l4 < 64; l4 += 4) {
          float4 g4 = *(const float4*)&g_s[sr*68 + l4];
          aa = fmaf(Mc_s[(l4+0)*33 + s2], g4.x, aa);
          aa = fmaf(Mc_s[(l4+1)*33 + s2], g4.y, aa);
          aa = fmaf(Mc_s[(l4+2)*33 + s2], g4.z, aa);
          aa = fmaf(Mc_s[(l4+3)*33 + s2], g4.w, aa);
        }
        uni[sr*36 + s2] = aa;
      };
      auto rowZ = [&](int s) {
        float acc = 0.0f;
#pragma unroll
        for (int s4 = 0; s4 < 32; s4 += 4) {
          float4 a4 = *(const float4*)&uni[s*36 + s4];
          acc = fmaf(Mc_s[lam*33 + s4+0], a4.x, acc);
          acc = fmaf(Mc_s[lam*33 + s4+1], a4.y, acc);
          acc = fmaf(Mc_s[lam*33 + s4+2], a4.z, acc);
          acc = fmaf(Mc_s[lam*33 + s4+3], a4.w, acc);
        }
        float gg = g_s[s*68 + lam];
        z_s[s*68 + lam] = z_s[s*68 + lam] - acc - q_r*gg;  // z' (mf added next dyn)
      };
      if (w == 1) {
        rowY1G(0); rowY1G(16);
        pairAG(0, 16);
        rowZ(0); rowZ(16);
      } else {
        const int base = (w - 2) * 5;
        const int st = base + ((base >= 15) ? 2 : 1);
        rowY1G(st); rowY1G(st+1); rowY1G(st+2); rowY1G(st+3); rowY1G(st+4);
        pairAG(st, st+1); pairAG(st+2, st+3); pairAG(st+4, st+4);
        rowZ(st); rowZ(st+1); rowZ(st+2); rowZ(st+3); rowZ(st+4);
      }
    }
    __syncthreads();  // B5
  }
}

extern "C" void kernel_launch(void* const* d_in, const int* in_sizes, int n_in,
                              void* d_out, int out_size, void* d_ws, size_t ws_size,
                              hipStream_t stream) {
  (void)in_sizes; (void)n_in; (void)out_size; (void)d_ws; (void)ws_size;
  nlf_kernel<<<dim3(B_), dim3(512), 0, stream>>>(
      (const float*)d_in[0], (const float*)d_in[1], (const float*)d_in[2],
      (const float*)d_in[3], (const float*)d_in[4], (const float*)d_in[5],
      (const float*)d_in[6], (const float*)d_in[7], (const float*)d_in[8],
      (const float*)d_in[9], (const float*)d_in[10], (float*)d_out);
}

// Round 4
// 12545.670 us; speedup vs baseline: 1.3017x; 1.2255x over previous
//
#include <hip/hip_runtime.h>
#include <cstdint>
#include <cstddef>

namespace {
constexpr int T_ = 500, S_ = 32, B_ = 128, L_ = 64, R_ = 8;

__device__ __forceinline__ float rdlane(float v, int l) {
  return __int_as_float(__builtin_amdgcn_readlane(__float_as_int(v), l));
}
template<int CTRL, int RM>
__device__ __forceinline__ float dppadd(float v) {
  int t = __builtin_amdgcn_update_dpp(0, __float_as_int(v), CTRL, RM, 0xf, false);
  return v + __int_as_float(t);
}
// full 64-lane sum; total lands in lane 63 (VALU-only, no DS)
__device__ __forceinline__ float wredsum(float v) {
  v = dppadd<0x111, 0xf>(v);   // row_shr:1
  v = dppadd<0x112, 0xf>(v);   // row_shr:2
  v = dppadd<0x114, 0xf>(v);   // row_shr:4
  v = dppadd<0x118, 0xf>(v);   // row_shr:8
  v = dppadd<0x142, 0xa>(v);   // row_bcast:15 -> rows 1,3
  v = dppadd<0x143, 0xc>(v);   // row_bcast:31 -> rows 2,3
  return v;
}
__device__ __forceinline__ float wsum(float v) {  // all-lanes result (step0 only)
  v += __shfl_xor(v, 1);  v += __shfl_xor(v, 2);  v += __shfl_xor(v, 4);
  v += __shfl_xor(v, 8);  v += __shfl_xor(v, 16); v += __shfl_xor(v, 32);
  return v;
}
__device__ __forceinline__ void gload16(const float* g, float* l) {
  __builtin_amdgcn_global_load_lds((const __attribute__((address_space(1))) uint32_t*)g,
                                   (__attribute__((address_space(3))) uint32_t*)l,
                                   16, 0, 0);
}
}  // namespace

// One block per batch element b. 512 threads = 8 waves.
// Key algebraic simplification: h_p = P_p^{-1} m_p is only consumed via
// u = P_p (h_p + k_t) = m_p + M_c(M_c^T k_t) + Q k_t  (Woodbury identity,
// exact) -> the 32x32 G/Cholesky/tri-solve path is never computed.
__global__ __launch_bounds__(512, 1) void nlf_kernel(
    const float* __restrict__ m0p, const float* __restrict__ q0p,
    const float* __restrict__ qp,  const float* __restrict__ kp,
    const float* __restrict__ Kp,  const float* __restrict__ Ap,
    const float* __restrict__ wp0p, const float* __restrict__ wf0p,
    const float* __restrict__ wp1p, const float* __restrict__ wp2p,
    const float* __restrict__ wfp,  float* __restrict__ outp)
{
  __shared__ __align__(16) float z_s[S_*68];      // carry z' (z - mf) / z_p_c
  __shared__ __align__(16) float g_s[S_*68];      // K@y1 per s
  __shared__ __align__(16) float Mc_s[L_*33];     // M_c[l][s]
  __shared__ __align__(16) float uni[1160];       // mp partial sums
  __shared__ __align__(16) float wp1b[2][S_*S_];
  __shared__ __align__(16) float wp2b[2][S_*L_];
  __shared__ __align__(16) float wf_s[S_*R_];
  __shared__ __align__(16) float Kt_s[L_*R_];
  __shared__ __align__(16) float v1t_s[S_*R_];
  __shared__ __align__(16) float KM_s[S_*R_];     // [s*8+r]
  __shared__ __align__(16) float M8_s[64];
  __shared__ __align__(16) float C8_s[64];
  __shared__ __align__(16) float tk_s[S_];        // Mc^T k_t
  __shared__ __align__(16) float th_s[S_];        // Mc^T gv (wave0 scratch)
  __shared__ __align__(16) float hv_s[L_];        // gv vector (wave0 scratch)
  __shared__ __align__(16) float mf_s[L_];
  __shared__ __align__(16) float qv_s[L_];
  __shared__ __align__(16) float q0v_s[L_];

  const int tid = threadIdx.x;
  const int lam = tid & 63;
  const int w   = tid >> 6;
  const int b   = blockIdx.x;

  float Areg[64];
#pragma unroll
  for (int j4 = 0; j4 < 16; ++j4) {
    float4 a4 = *(const float4*)(Ap + (size_t)lam*64 + j4*4);
    Areg[4*j4+0]=a4.x; Areg[4*j4+1]=a4.y; Areg[4*j4+2]=a4.z; Areg[4*j4+3]=a4.w;
  }
  const float q_r  = qp[lam];
  const float qs_r = sqrtf(q_r);
  const float q0_r = q0p[lam];
  const float m0_r = m0p[lam];
  if (tid < 64) { qv_s[tid] = q_r; q0v_s[tid] = q0_r; }

  float Kreg[8];
  {
    const float* kb = Kp + (size_t)b*(L_*R_) + lam*R_;
    float4 ka = *(const float4*)kb, kb4 = *(const float4*)(kb+4);
    Kreg[0]=ka.x;Kreg[1]=ka.y;Kreg[2]=ka.z;Kreg[3]=ka.w;
    Kreg[4]=kb4.x;Kreg[5]=kb4.y;Kreg[6]=kb4.z;Kreg[7]=kb4.w;
  }
  float kt_r = kp[(size_t)b*L_ + lam];

  // ---- prologue async loads ----
  if (w == 0) {                       // wp1[0] -> wp1b[1]
#pragma unroll
    for (int m = 0; m < 4; ++m) {
      int f = m*256 + lam*4, s = f >> 5, c = f & 31;
      gload16(wp1p + ((size_t)s*B_ + b)*S_ + c, &wp1b[1][f]);
    }
  } else if (w == 1 || w == 2) {      // wp2[0] -> wp2b[1]
#pragma unroll
    for (int m = 0; m < 4; ++m) {
      int f = (w-1)*1024 + m*256 + lam*4, s = f >> 6, c = f & 63;
      gload16(wp2p + ((size_t)s*B_ + b)*L_ + c, &wp2b[1][f]);
    }
  } else if (w == 3) {                // wf0 -> wf_s ; K[0] -> Kt_s
    { int f = lam*4, s = f >> 3, c = f & 7;
      gload16(wf0p + ((size_t)s*B_ + b)*R_ + c, &wf_s[f]); }
#pragma unroll
    for (int m = 0; m < 2; ++m) {
      int f = m*256 + lam*4;
      gload16(Kp + (size_t)b*(L_*R_) + f, &Kt_s[f]);
    }
  } else if (w == 4 || w == 5) {      // w_p0 -> wp2b[0]
#pragma unroll
    for (int m = 0; m < 4; ++m) {
      int f = (w-4)*1024 + m*256 + lam*4, s = f >> 6, c = f & 63;
      gload16(wp0p + ((size_t)s*B_ + b)*L_ + c, &wp2b[0][f]);
    }
  }
  __syncthreads();

  // 8x8 SPD: C8_s -> M8_s = inv(C8) via in-register Cholesky (rows in lanes 0-7)
  auto chol8M8 = [&]() {
    const int i8 = lam & 7;
    float c8[8], rd8 = 0.0f;
#pragma unroll
    for (int k = 0; k < 8; ++k) c8[k] = C8_s[i8*8 + k];
#pragma unroll
    for (int j = 0; j < 8; ++j) {
      float dj = rdlane(c8[j], j);
      float rinv = rsqrtf(dj);
      if (i8 == j) rd8 = rinv;
      c8[j] *= rinv;
#pragma unroll
      for (int k = j+1; k < 8; ++k)
        c8[k] = fmaf(-rdlane(c8[j], k), c8[j], c8[k]);
    }
    float w8[8];                       // lane holds column i8 of W = L^-1
#pragma unroll
    for (int i = 0; i < 8; ++i) {
      float sacc = (i == i8) ? 1.0f : 0.0f;
#pragma unroll
      for (int k = 0; k < i; ++k)
        sacc = fmaf(-rdlane(c8[k], i), w8[k], sacc);
      w8[i] = sacc * rdlane(rd8, i);
    }
#pragma unroll
    for (int i = 0; i < 8; ++i) {      // M8 = W^T W
      float msum = 0.0f;
#pragma unroll
      for (int k = 0; k < 8; ++k)
        msum = fmaf(rdlane(w8[k], i), w8[k], msum);
      if (lam < 8) M8_s[i*8 + lam] = msum;
    }
  };

  // ================= step 0 =================
  {
    const float Pp = q0_r;
    const float h0 = m0_r / Pp + kt_r;
    if (w == 0) {
      const int r1 = lam >> 3, r2 = lam & 7;
      float acc = 0.0f;
#pragma unroll 4
      for (int l = 0; l < 64; ++l)
        acc = fmaf(Kt_s[l*8 + r1] * q0v_s[l], Kt_s[l*8 + r2], acc);
      C8_s[lam] = acc + (r1 == r2 ? 1.0f : 0.0f);
      chol8M8();
      float t8[8];
#pragma unroll
      for (int r = 0; r < 8; ++r) t8[r] = wsum(Pp * Kreg[r] * h0);
      float acc2 = 0.0f;
#pragma unroll
      for (int r1i = 0; r1i < 8; ++r1i) {
        float4 ma = *(const float4*)&M8_s[r1i*8];
        float4 mb = *(const float4*)&M8_s[r1i*8+4];
        float y = ma.x*t8[0]+ma.y*t8[1]+ma.z*t8[2]+ma.w*t8[3]
                + mb.x*t8[4]+mb.y*t8[5]+mb.z*t8[6]+mb.w*t8[7];
        acc2 = fmaf(Kreg[r1i], y, acc2);
      }
      float m0f = Pp*h0 - Pp*acc2;
      mf_s[lam] = m0f;
      outp[(size_t)b*L_ + lam] = m0f;
    }
    __syncthreads();

    const float qs0 = sqrtf(q0_r);
#pragma unroll
    for (int i = 0; i < 4; ++i) {
      const int s = 4*w + i;
      float zp = qs0 * wp2b[0][s*64 + lam];
      float v1[8];
#pragma unroll
      for (int r = 0; r < 8; ++r)
        v1[r] = wsum(Kreg[r] * zp) + wf_s[s*8 + r];
      float acc = 0.0f;
#pragma unroll
      for (int r1i = 0; r1i < 8; ++r1i) {
        float4 ma = *(const float4*)&M8_s[r1i*8];
        float4 mb = *(const float4*)&M8_s[r1i*8+4];
        float y = ma.x*v1[0]+ma.y*v1[1]+ma.z*v1[2]+ma.w*v1[3]
                + mb.x*v1[4]+mb.y*v1[5]+mb.z*v1[6]+mb.w*v1[7];
        acc = fmaf(Kreg[r1i], y, acc);
      }
      z_s[s*68 + lam] = zp - Pp*acc;   // z' excludes m_f (added in next dyn)
    }
  }
  __syncthreads();

  // ================= steps 1..T-1 =================
  for (int t = 1; t < T_; ++t) {
    const int cb = t & 1, nb = cb ^ 1;

    // per-lane K/k reload (global; hidden under P1, used from P2 on)
    {
      const float* kb = Kp + ((size_t)t*B_ + b)*(L_*R_) + lam*R_;
      float4 ka = *(const float4*)kb, kb4 = *(const float4*)(kb+4);
      Kreg[0]=ka.x;Kreg[1]=ka.y;Kreg[2]=ka.z;Kreg[3]=ka.w;
      Kreg[4]=kb4.x;Kreg[5]=kb4.y;Kreg[6]=kb4.z;Kreg[7]=kb4.w;
      kt_r = kp[((size_t)t*B_ + b)*L_ + lam];
    }

    // ---- P1: dyn on z = z' + mf ----
    float dmf = 0.0f;
#pragma unroll
    for (int j4 = 0; j4 < 16; ++j4) {
      float4 m4 = *(const float4*)&mf_s[4*j4];
      dmf = fmaf(m4.x, Areg[4*j4+0], dmf);
      dmf = fmaf(m4.y, Areg[4*j4+1], dmf);
      dmf = fmaf(m4.z, Areg[4*j4+2], dmf);
      dmf = fmaf(m4.w, Areg[4*j4+3], dmf);
    }
    const float mfl = mf_s[lam];
    float zn[4];
#pragma unroll
    for (int i = 0; i < 4; ++i) {
      const int s = 4*w + i;
      float a0=0,a1=0,a2=0,a3=0;
#pragma unroll
      for (int j4 = 0; j4 < 16; ++j4) {
        float4 zb = *(const float4*)&z_s[s*68 + 4*j4];
        a0 = fmaf(zb.x, Areg[4*j4+0], a0);
        a1 = fmaf(zb.y, Areg[4*j4+1], a1);
        a2 = fmaf(zb.z, Areg[4*j4+2], a2);
        a3 = fmaf(zb.w, Areg[4*j4+3], a3);
      }
      float x = ((a0+a1)+(a2+a3)) + dmf;
      float e = __expf(2.0f*x);
      float tnh = 1.0f - 2.0f/(e + 1.0f);
      zn[i] = (z_s[s*68 + lam] + mfl) + 0.1f*tnh;
    }
    uni[w*68 + lam] = zn[0]+zn[1]+zn[2]+zn[3];
    __syncthreads();  // B1

    // ---- P0: async prefetch issued here; drains at B2 ----
    if (w == 0) {
      if (t < T_-1) {
#pragma unroll
        for (int m = 0; m < 4; ++m) {
          int f = m*256 + lam*4, s = f >> 5, c = f & 31;
          gload16(wp1p + (((size_t)t*S_ + s)*B_ + b)*S_ + c, &wp1b[nb][f]);
        }
      }
    } else if (w == 1 || w == 2) {
      if (t < T_-1) {
#pragma unroll
        for (int m = 0; m < 4; ++m) {
          int f = (w-1)*1024 + m*256 + lam*4, s = f >> 6, c = f & 63;
          gload16(wp2p + (((size_t)t*S_ + s)*B_ + b)*L_ + c, &wp2b[nb][f]);
        }
      }
    } else if (w == 3) {
      { int f = lam*4, s = f >> 3, c = f & 7;
        gload16(wfp + (((size_t)(t-1)*S_ + s)*B_ + b)*R_ + c, &wf_s[f]); }
#pragma unroll
      for (int m = 0; m < 2; ++m) {
        int f = m*256 + lam*4;
        gload16(Kp + ((size_t)t*B_ + b)*(L_*R_) + f, &Kt_s[f]);
      }
    }

    // ---- P2: m_p, M_c, KM = K^T Mc, tk = Mc^T k_t ----
    float mp = 0.0f;
#pragma unroll
    for (int ww = 0; ww < 8; ++ww) mp += uni[ww*68 + lam];
    mp *= 0.03125f;
    float mcv[4];
#pragma unroll
    for (int i = 0; i < 4; ++i) {
      const int s = 4*w + i;
      mcv[i] = (zn[i] - mp) * 0.17677669529663689f;
      Mc_s[lam*33 + s] = mcv[i];
      float tkv = wredsum(mcv[i] * kt_r);
      float kmv[8];
#pragma unroll
      for (int r = 0; r < 8; ++r) kmv[r] = wredsum(mcv[i] * Kreg[r]);
      if (lam == 63) {
        tk_s[s] = tkv;
        *(float4*)&KM_s[s*8]   = make_float4(kmv[0],kmv[1],kmv[2],kmv[3]);
        *(float4*)&KM_s[s*8+4] = make_float4(kmv[4],kmv[5],kmv[6],kmv[7]);
      }
    }
    __syncthreads();  // B2

    // ---- P3: zprows (all waves) + wave0 {u, t8} + wave1 {C8, M8} ----
    auto zprow = [&](int s) {
      float acc = 0.0f;
#pragma unroll
      for (int p4 = 0; p4 < 32; p4 += 4) {
        float4 wb = *(const float4*)&wp1b[cb][s*32 + p4];
        acc = fmaf(Mc_s[lam*33 + p4+0], wb.x, acc);
        acc = fmaf(Mc_s[lam*33 + p4+1], wb.y, acc);
        acc = fmaf(Mc_s[lam*33 + p4+2], wb.z, acc);
        acc = fmaf(Mc_s[lam*33 + p4+3], wb.w, acc);
      }
      float zp = acc + qs_r * wp2b[cb][s*64 + lam];
      z_s[s*68 + lam] = zp;
      float vv[8];
#pragma unroll
      for (int r = 0; r < 8; ++r) vv[r] = wredsum(Kreg[r] * zp);
      if (lam == 63) {
        float4 wfa = *(const float4*)&wf_s[s*8];
        float4 wfb = *(const float4*)&wf_s[s*8+4];
        *(float4*)&v1t_s[s*8]   = make_float4(vv[0]+wfa.x, vv[1]+wfa.y,
                                              vv[2]+wfa.z, vv[3]+wfa.w);
        *(float4*)&v1t_s[s*8+4] = make_float4(vv[4]+wfb.x, vv[5]+wfb.y,
                                              vv[6]+wfb.z, vv[7]+wfb.w);
      }
    };

    float u_r = 0.0f, t8s[8];
    if (w == 0) {
      zprow(0); zprow(1); zprow(2); zprow(3);
      // u = m_p + Mc tk + q k_t   (exact substitute for P_p (h_p + k_t))
      float mctk = 0.0f;
#pragma unroll
      for (int s4 = 0; s4 < 32; s4 += 4) {
        float4 tb = *(const float4*)&tk_s[s4];
        mctk = fmaf(Mc_s[lam*33 + s4+0], tb.x, mctk);
        mctk = fmaf(Mc_s[lam*33 + s4+1], tb.y, mctk);
        mctk = fmaf(Mc_s[lam*33 + s4+2], tb.z, mctk);
        mctk = fmaf(Mc_s[lam*33 + s4+3], tb.w, mctk);
      }
      u_r = mp + mctk + q_r * kt_r;
#pragma unroll
      for (int r = 0; r < 8; ++r) {
        float v = wredsum(Kreg[r] * u_r);
        t8s[r] = rdlane(v, 63);
      }
    } else if (w == 1) {
      zprow(4); zprow(5);
      const int r1 = lam >> 3, r2 = lam & 7;
      float acc = 0.0f;
#pragma unroll 4
      for (int s = 0; s < 32; ++s)
        acc = fmaf(KM_s[s*8 + r1], KM_s[s*8 + r2], acc);
#pragma unroll 4
      for (int l = 0; l < 64; ++l)
        acc = fmaf(Kt_s[l*8 + r1] * qv_s[l], Kt_s[l*8 + r2], acc);
      C8_s[lam] = acc + (r1 == r2 ? 1.0f : 0.0f);
      chol8M8();
    } else if (w <= 5) {
      const int st = 6 + (w - 2) * 4;
      zprow(st); zprow(st+1); zprow(st+2); zprow(st+3);
    } else {
      const int st = 22 + (w - 6) * 5;
      zprow(st); zprow(st+1); zprow(st+2); zprow(st+3); zprow(st+4);
    }
    __syncthreads();  // B3

    // ---- P4 split: wave0 = m_f tail; waves1-7 = y1/g/ag/z rows ----
    if (w == 0) {
      // gv = K M8 t8
      float gvv = 0.0f;
#pragma unroll
      for (int r1i = 0; r1i < 8; ++r1i) {
        float4 ma = *(const float4*)&M8_s[r1i*8];
        float4 mb = *(const float4*)&M8_s[r1i*8+4];
        float y = ma.x*t8s[0]+ma.y*t8s[1]+ma.z*t8s[2]+ma.w*t8s[3]
                + mb.x*t8s[4]+mb.y*t8s[5]+mb.z*t8s[6]+mb.w*t8s[7];
        gvv = fmaf(Kreg[r1i], y, gvv);
      }
      hv_s[lam] = gvv;
      // tg = Mc^T gv
      const int s2w = lam & 31;
      float tgv = 0.0f;
#pragma unroll
      for (int l = 0; l < 64; l += 4) {
        float4 gb = *(const float4*)&hv_s[l];
        tgv = fmaf(Mc_s[(l+0)*33 + s2w], gb.x, tgv);
        tgv = fmaf(Mc_s[(l+1)*33 + s2w], gb.y, tgv);
        tgv = fmaf(Mc_s[(l+2)*33 + s2w], gb.z, tgv);
        tgv = fmaf(Mc_s[(l+3)*33 + s2w], gb.w, tgv);
      }
      if (lam < 32) th_s[lam] = tgv;
      // mf = u - Mc tg - q gv
      float mctg = 0.0f;
#pragma unroll
      for (int s4 = 0; s4 < 32; s4 += 4) {
        float4 tb = *(const float4*)&th_s[s4];
        mctg = fmaf(Mc_s[lam*33 + s4+0], tb.x, mctg);
        mctg = fmaf(Mc_s[lam*33 + s4+1], tb.y, mctg);
        mctg = fmaf(Mc_s[lam*33 + s4+2], tb.z, mctg);
        mctg = fmaf(Mc_s[lam*33 + s4+3], tb.w, mctg);
      }
      const float mf_r = u_r - mctg - q_r*gvv;
      mf_s[lam] = mf_r;
      outp[((size_t)t*B_ + b)*L_ + lam] = mf_r;
    } else {
      auto rowY1G = [&](int s) {
        float4 va = *(const float4*)&v1t_s[s*8];
        float4 vb = *(const float4*)&v1t_s[s*8+4];
        float gg = 0.0f;
#pragma unroll
        for (int r1i = 0; r1i < 8; ++r1i) {
          float4 ma = *(const float4*)&M8_s[r1i*8];
          float4 mb = *(const float4*)&M8_s[r1i*8+4];
          float y = ma.x*va.x+ma.y*va.y+ma.z*va.z+ma.w*va.w
                  + mb.x*vb.x+mb.y*vb.y+mb.z*vb.z+mb.w*vb.w;
          gg = fmaf(Kreg[r1i], y, gg);
        }
        g_s[s*68 + lam] = gg;
      };
      auto pairAG = [&](int sa, int sb) {
        const int s2 = lam & 31;
        const int sr = (lam >= 32) ? sb : sa;
        float aa = 0.0f;
#pragma unroll
        for (int l4 = 0; l4 < 64; l4 += 4) {
          float4 g4 = *(const float4*)&g_s[sr*68 + l4];
          aa = fmaf(Mc_s[(l4+0)*33 + s2], g4.x, aa);
          aa = fmaf(Mc_s[(l4+1)*33 + s2], g4.y, aa);
          aa = fmaf(Mc_s[(l4+2)*33 + s2], g4.z, aa);
          aa = fmaf(Mc_s[(l4+3)*33 + s2], g4.w, aa);
        }
        uni[sr*36 + s2] = aa;
      };
      auto rowZ = [&](int s) {
        float acc = 0.0f;
#pragma unroll
        for (int s4 = 0; s4 < 32; s4 += 4) {
          float4 a4 = *(const float4*)&uni[s*36 + s4];
          acc = fmaf(Mc_s[lam*33 + s4+0], a4.x, acc);
          acc = fmaf(Mc_s[lam*33 + s4+1], a4.y, acc);
          acc = fmaf(Mc_s[lam*33 + s4+2], a4.z, acc);
          acc = fmaf(Mc_s[lam*33 + s4+3], a4.w, acc);
        }
        float gg = g_s[s*68 + lam];
        z_s[s*68 + lam] = z_s[s*68 + lam] - acc - q_r*gg;  // z' (mf added next dyn)
      };
      if (w <= 4) {
        const int st = (w - 1) * 5;
        rowY1G(st); rowY1G(st+1); rowY1G(st+2); rowY1G(st+3); rowY1G(st+4);
        pairAG(st, st+1); pairAG(st+2, st+3); pairAG(st+4, st+4);
        rowZ(st); rowZ(st+1); rowZ(st+2); rowZ(st+3); rowZ(st+4);
      } else {
        const int st = 20 + (w - 5) * 4;
        rowY1G(st); rowY1G(st+1); rowY1G(st+2); rowY1G(st+3);
        pairAG(st, st+1); pairAG(st+2, st+3);
        rowZ(st); rowZ(st+1); rowZ(st+2); rowZ(st+3);
      }
    }
    __syncthreads();  // B4
  }
}

extern "C" void kernel_launch(void* const* d_in, const int* in_sizes, int n_in,
                              void* d_out, int out_size, void* d_ws, size_t ws_size,
                              hipStream_t stream) {
  (void)in_sizes; (void)n_in; (void)out_size; (void)d_ws; (void)ws_size;
  nlf_kernel<<<dim3(B_), dim3(512), 0, stream>>>(
      (const float*)d_in[0], (const float*)d_in[1], (const float*)d_in[2],
      (const float*)d_in[3], (const float*)d_in[4], (const float*)d_in[5],
      (const float*)d_in[6], (const float*)d_in[7], (const float*)d_in[8],
      (const float*)d_in[9], (const float*)d_in[10], (float*)d_out);
}

// Round 6
// 11584.943 us; speedup vs baseline: 1.4096x; 1.0829x over previous
//
#include <hip/hip_runtime.h>
#include <cstdint>
#include <cstddef>

namespace {
constexpr int T_ = 500, S_ = 32, B_ = 128, L_ = 64, R_ = 8;

__device__ __forceinline__ float rdlane(float v, int l) {
  return __int_as_float(__builtin_amdgcn_readlane(__float_as_int(v), l));
}
template<int CTRL, int RM>
__device__ __forceinline__ float dppadd(float v) {
  int t = __builtin_amdgcn_update_dpp(0, __float_as_int(v), CTRL, RM, 0xf, false);
  return v + __int_as_float(t);
}
// full 64-lane sum; total lands in lane 63 (VALU-only, no DS)
__device__ __forceinline__ float wredsum(float v) {
  v = dppadd<0x111, 0xf>(v);   // row_shr:1
  v = dppadd<0x112, 0xf>(v);   // row_shr:2
  v = dppadd<0x114, 0xf>(v);   // row_shr:4
  v = dppadd<0x118, 0xf>(v);   // row_shr:8
  v = dppadd<0x142, 0xa>(v);   // row_bcast:15 -> rows 1,3
  v = dppadd<0x143, 0xc>(v);   // row_bcast:31 -> rows 2,3
  return v;
}
__device__ __forceinline__ float wsum(float v) {  // all-lanes result (step0 only)
  v += __shfl_xor(v, 1);  v += __shfl_xor(v, 2);  v += __shfl_xor(v, 4);
  v += __shfl_xor(v, 8);  v += __shfl_xor(v, 16); v += __shfl_xor(v, 32);
  return v;
}
__device__ __forceinline__ void gload16(const float* g, float* l) {
  __builtin_amdgcn_global_load_lds((const __attribute__((address_space(1))) uint32_t*)g,
                                   (__attribute__((address_space(3))) uint32_t*)l,
                                   16, 0, 0);
}
// barrier that drains LDS ops but lets global loads/stores ride (vmcnt untouched)
__device__ __forceinline__ void bar_lgkm() {
  asm volatile("s_waitcnt lgkmcnt(0)\n\ts_barrier" ::: "memory");
}
}  // namespace

// One block per batch element b. 512 threads = 8 waves; wave w owns ensemble
// rows 4w..4w+3 in EVERY phase, so the ensemble state z' lives in registers.
__global__ __launch_bounds__(512, 1) void nlf_kernel(
    const float* __restrict__ m0p, const float* __restrict__ q0p,
    const float* __restrict__ qp,  const float* __restrict__ kp,
    const float* __restrict__ Kp,  const float* __restrict__ Ap,
    const float* __restrict__ wp0p, const float* __restrict__ wf0p,
    const float* __restrict__ wp1p, const float* __restrict__ wp2p,
    const float* __restrict__ wfp,  float* __restrict__ outp)
{
  __shared__ __align__(16) float Mc_s[L_*33];     // M_c[l][s]
  __shared__ __align__(16) float uni[8*68];       // mp partial sums
  __shared__ __align__(16) float wp1b[2][S_*S_];
  __shared__ __align__(16) float wp2b[2][S_*L_];
  __shared__ __align__(16) float wf_s[S_*R_];
  __shared__ __align__(16) float Kt_s[L_*R_];
  __shared__ __align__(16) float v1t_s[S_*R_];
  __shared__ __align__(16) float KM_s[S_*R_];     // [s*8+r]
  __shared__ __align__(16) float M8_s[64];
  __shared__ __align__(16) float C8_s[64];
  __shared__ __align__(16) float tk_s[S_];        // Mc^T k_t
  __shared__ __align__(16) float mf_s[L_];
  __shared__ __align__(16) float qv_s[L_];
  __shared__ __align__(16) float q0v_s[L_];

  const int tid = threadIdx.x;
  const int lam = tid & 63;
  const int w   = tid >> 6;
  const int b   = blockIdx.x;

  float Areg[64];
#pragma unroll
  for (int j4 = 0; j4 < 16; ++j4) {
    float4 a4 = *(const float4*)(Ap + (size_t)lam*64 + j4*4);
    Areg[4*j4+0]=a4.x; Areg[4*j4+1]=a4.y; Areg[4*j4+2]=a4.z; Areg[4*j4+3]=a4.w;
  }
  const float q_r  = qp[lam];
  const float qs_r = sqrtf(q_r);
  const float q0_r = q0p[lam];
  const float m0_r = m0p[lam];
  if (tid < 64) { qv_s[tid] = q_r; q0v_s[tid] = q0_r; }

  float Kreg[8];
  {
    const float* kb = Kp + (size_t)b*(L_*R_) + lam*R_;
    float4 ka = *(const float4*)kb, kb4 = *(const float4*)(kb+4);
    Kreg[0]=ka.x;Kreg[1]=ka.y;Kreg[2]=ka.z;Kreg[3]=ka.w;
    Kreg[4]=kb4.x;Kreg[5]=kb4.y;Kreg[6]=kb4.z;Kreg[7]=kb4.w;
  }
  float kt_r = kp[(size_t)b*L_ + lam];
  float zreg[4];   // z' rows 4w..4w+3, element lam

  // ---- prologue async loads ----
  if (w == 0) {                       // wp1[0] -> wp1b[1]
#pragma unroll
    for (int m = 0; m < 4; ++m) {
      int f = m*256 + lam*4, s = f >> 5, c = f & 31;
      gload16(wp1p + ((size_t)s*B_ + b)*S_ + c, &wp1b[1][f]);
    }
  } else if (w == 1 || w == 2) {      // wp2[0] -> wp2b[1]
#pragma unroll
    for (int m = 0; m < 4; ++m) {
      int f = (w-1)*1024 + m*256 + lam*4, s = f >> 6, c = f & 63;
      gload16(wp2p + ((size_t)s*B_ + b)*L_ + c, &wp2b[1][f]);
    }
  } else if (w == 3) {                // wf0 -> wf_s ; K[0] -> Kt_s
    { int f = lam*4, s = f >> 3, c = f & 7;
      gload16(wf0p + ((size_t)s*B_ + b)*R_ + c, &wf_s[f]); }
#pragma unroll
    for (int m = 0; m < 2; ++m) {
      int f = m*256 + lam*4;
      gload16(Kp + (size_t)b*(L_*R_) + f, &Kt_s[f]);
    }
  } else if (w == 4 || w == 5) {      // w_p0 -> wp2b[0]
#pragma unroll
    for (int m = 0; m < 4; ++m) {
      int f = (w-4)*1024 + m*256 + lam*4, s = f >> 6, c = f & 63;
      gload16(wp0p + ((size_t)s*B_ + b)*L_ + c, &wp2b[0][f]);
    }
  }
  __syncthreads();

  // 8x8 SPD: C8_s -> M8_s = inv(C8) via in-register Cholesky (rows in lanes 0-7)
  auto chol8M8 = [&]() {
    const int i8 = lam & 7;
    float c8[8], rd8 = 0.0f;
#pragma unroll
    for (int k = 0; k < 8; ++k) c8[k] = C8_s[i8*8 + k];
#pragma unroll
    for (int j = 0; j < 8; ++j) {
      float dj = rdlane(c8[j], j);
      float rinv = rsqrtf(dj);
      if (i8 == j) rd8 = rinv;
      c8[j] *= rinv;
#pragma unroll
      for (int k = j+1; k < 8; ++k)
        c8[k] = fmaf(-rdlane(c8[j], k), c8[j], c8[k]);
    }
    float w8[8];
#pragma unroll
    for (int i = 0; i < 8; ++i) {
      float sacc = (i == i8) ? 1.0f : 0.0f;
#pragma unroll
      for (int k = 0; k < i; ++k)
        sacc = fmaf(-rdlane(c8[k], i), w8[k], sacc);
      w8[i] = sacc * rdlane(rd8, i);
    }
#pragma unroll
    for (int i = 0; i < 8; ++i) {
      float msum = 0.0f;
#pragma unroll
      for (int k = 0; k < 8; ++k)
        msum = fmaf(rdlane(w8[k], i), w8[k], msum);
      if (lam < 8) M8_s[i*8 + lam] = msum;
    }
  };

  // ================= step 0 =================
  {
    const float Pp = q0_r;
    const float h0 = m0_r / Pp + kt_r;
    if (w == 0) {
      const int r1 = lam >> 3, r2 = lam & 7;
      float acc = 0.0f;
#pragma unroll 4
      for (int l = 0; l < 64; ++l)
        acc = fmaf(Kt_s[l*8 + r1] * q0v_s[l], Kt_s[l*8 + r2], acc);
      C8_s[lam] = acc + (r1 == r2 ? 1.0f : 0.0f);
      chol8M8();
      float t8[8];
#pragma unroll
      for (int r = 0; r < 8; ++r) t8[r] = wsum(Pp * Kreg[r] * h0);
      float acc2 = 0.0f;
#pragma unroll
      for (int r1i = 0; r1i < 8; ++r1i) {
        float4 ma = *(const float4*)&M8_s[r1i*8];
        float4 mb = *(const float4*)&M8_s[r1i*8+4];
        float y = ma.x*t8[0]+ma.y*t8[1]+ma.z*t8[2]+ma.w*t8[3]
                + mb.x*t8[4]+mb.y*t8[5]+mb.z*t8[6]+mb.w*t8[7];
        acc2 = fmaf(Kreg[r1i], y, acc2);
      }
      float m0f = Pp*h0 - Pp*acc2;
      mf_s[lam] = m0f;
      outp[(size_t)b*L_ + lam] = m0f;
    }
    __syncthreads();

    const float qs0 = sqrtf(q0_r);
#pragma unroll
    for (int i = 0; i < 4; ++i) {
      const int s = 4*w + i;
      float zp = qs0 * wp2b[0][s*64 + lam];
      float v1[8];
#pragma unroll
      for (int r = 0; r < 8; ++r)
        v1[r] = wsum(Kreg[r] * zp) + wf_s[s*8 + r];
      float acc = 0.0f;
#pragma unroll
      for (int r1i = 0; r1i < 8; ++r1i) {
        float4 ma = *(const float4*)&M8_s[r1i*8];
        float4 mb = *(const float4*)&M8_s[r1i*8+4];
        float y = ma.x*v1[0]+ma.y*v1[1]+ma.z*v1[2]+ma.w*v1[3]
                + mb.x*v1[4]+mb.y*v1[5]+mb.z*v1[6]+mb.w*v1[7];
        acc = fmaf(Kreg[r1i], y, acc);
      }
      zreg[i] = zp - Pp*acc;   // z' excludes m_f (added in next dyn)
    }
  }
  __syncthreads();

  // ================= steps 1..T-1 =================
  for (int t = 1; t < T_; ++t) {
    const int cb = t & 1, nb = cb ^ 1;

    // per-lane K/k reload (global; hidden under P1, used from P2 on)
    {
      const float* kb = Kp + ((size_t)t*B_ + b)*(L_*R_) + lam*R_;
      float4 ka = *(const float4*)kb, kb4 = *(const float4*)(kb+4);
      Kreg[0]=ka.x;Kreg[1]=ka.y;Kreg[2]=ka.z;Kreg[3]=ka.w;
      Kreg[4]=kb4.x;Kreg[5]=kb4.y;Kreg[6]=kb4.z;Kreg[7]=kb4.w;
      kt_r = kp[((size_t)t*B_ + b)*L_ + lam];
    }

    // ---- P1: dyn on z = z' + mf (z rows broadcast via readlane from zreg) ----
    float dmf = 0.0f;
#pragma unroll
    for (int j4 = 0; j4 < 16; ++j4) {
      float4 m4 = *(const float4*)&mf_s[4*j4];
      dmf = fmaf(m4.x, Areg[4*j4+0], dmf);
      dmf = fmaf(m4.y, Areg[4*j4+1], dmf);
      dmf = fmaf(m4.z, Areg[4*j4+2], dmf);
      dmf = fmaf(m4.w, Areg[4*j4+3], dmf);
    }
    const float mfl = mf_s[lam];
    float zn[4];
#pragma unroll
    for (int i = 0; i < 4; ++i) {
      float a0 = 0.0f, a1 = 0.0f;
#pragma unroll
      for (int j = 0; j < 64; j += 2) {
        a0 = fmaf(rdlane(zreg[i], j),   Areg[j],   a0);
        a1 = fmaf(rdlane(zreg[i], j+1), Areg[j+1], a1);
      }
      float x = (a0 + a1) + dmf;
      float e = __expf(2.0f*x);
      float tnh = 1.0f - 2.0f/(e + 1.0f);
      zn[i] = (zreg[i] + mfl) + 0.1f*tnh;
    }
    uni[w*68 + lam] = zn[0]+zn[1]+zn[2]+zn[3];
    bar_lgkm();  // B1

    // ---- P0: async prefetch; drains at B2 (syncthreads) ----
    if (w == 0) {
      if (t < T_-1) {
#pragma unroll
        for (int m = 0; m < 4; ++m) {
          int f = m*256 + lam*4, s = f >> 5, c = f & 31;
          gload16(wp1p + (((size_t)t*S_ + s)*B_ + b)*S_ + c, &wp1b[nb][f]);
        }
      }
    } else if (w == 1 || w == 2) {
      if (t < T_-1) {
#pragma unroll
        for (int m = 0; m < 4; ++m) {
          int f = (w-1)*1024 + m*256 + lam*4, s = f >> 6, c = f & 63;
          gload16(wp2p + (((size_t)t*S_ + s)*B_ + b)*L_ + c, &wp2b[nb][f]);
        }
      }
    } else if (w == 3) {
      { int f = lam*4, s = f >> 3, c = f & 7;
        gload16(wfp + (((size_t)(t-1)*S_ + s)*B_ + b)*R_ + c, &wf_s[f]); }
#pragma unroll
      for (int m = 0; m < 2; ++m) {
        int f = m*256 + lam*4;
        gload16(Kp + ((size_t)t*B_ + b)*(L_*R_) + f, &Kt_s[f]);
      }
    }

    // ---- P2: m_p, M_c, KM = K^T Mc, tk = Mc^T k_t (DPP) ----
    float mp = 0.0f;
#pragma unroll
    for (int ww = 0; ww < 8; ++ww) mp += uni[ww*68 + lam];
    mp *= 0.03125f;
    float mcv[4];
#pragma unroll
    for (int i = 0; i < 4; ++i) {
      const int s = 4*w + i;
      mcv[i] = (zn[i] - mp) * 0.17677669529663689f;
      Mc_s[lam*33 + s] = mcv[i];
      float tkv = wredsum(mcv[i] * kt_r);
      float kmv[8];
#pragma unroll
      for (int r = 0; r < 8; ++r) kmv[r] = wredsum(mcv[i] * Kreg[r]);
      if (lam == 63) {
        tk_s[s] = tkv;
        *(float4*)&KM_s[s*8]   = make_float4(kmv[0],kmv[1],kmv[2],kmv[3]);
        *(float4*)&KM_s[s*8+4] = make_float4(kmv[4],kmv[5],kmv[6],kmv[7]);
      }
    }
    __syncthreads();  // B2 (full: drains prefetch vmcnt)

    // per-lane Mc row into registers (reused by P3 and P4)
    float mcrow[32];
#pragma unroll
    for (int s2 = 0; s2 < 32; ++s2) mcrow[s2] = Mc_s[lam*33 + s2];

    // ---- P3: zprows (regs) + wave0 {u, t8} + wave1 {C8, M8} ----
    float u_r = 0.0f, t8s[8];
#pragma unroll
    for (int r = 0; r < 8; ++r) t8s[r] = 0.0f;
#pragma unroll
    for (int i = 0; i < 4; ++i) {
      const int s = 4*w + i;
      float acc = 0.0f;
#pragma unroll
      for (int p4 = 0; p4 < 32; p4 += 4) {
        float4 wb = *(const float4*)&wp1b[cb][s*32 + p4];
        acc = fmaf(mcrow[p4+0], wb.x, acc);
        acc = fmaf(mcrow[p4+1], wb.y, acc);
        acc = fmaf(mcrow[p4+2], wb.z, acc);
        acc = fmaf(mcrow[p4+3], wb.w, acc);
      }
      float zp = acc + qs_r * wp2b[cb][s*64 + lam];
      zreg[i] = zp;
      float vv[8];
#pragma unroll
      for (int r = 0; r < 8; ++r) vv[r] = wredsum(Kreg[r] * zp);
      if (lam == 63) {
        float4 wfa = *(const float4*)&wf_s[s*8];
        float4 wfb = *(const float4*)&wf_s[s*8+4];
        *(float4*)&v1t_s[s*8]   = make_float4(vv[0]+wfa.x, vv[1]+wfa.y,
                                              vv[2]+wfa.z, vv[3]+wfa.w);
        *(float4*)&v1t_s[s*8+4] = make_float4(vv[4]+wfb.x, vv[5]+wfb.y,
                                              vv[6]+wfb.z, vv[7]+wfb.w);
      }
    }
    if (w == 0) {
      // u = m_p + Mc tk + q k_t (Woodbury); t8 = K^T u
      float mctk = 0.0f;
#pragma unroll
      for (int s4 = 0; s4 < 32; s4 += 4) {
        float4 tb = *(const float4*)&tk_s[s4];
        mctk = fmaf(mcrow[s4+0], tb.x, mctk);
        mctk = fmaf(mcrow[s4+1], tb.y, mctk);
        mctk = fmaf(mcrow[s4+2], tb.z, mctk);
        mctk = fmaf(mcrow[s4+3], tb.w, mctk);
      }
      u_r = mp + mctk + q_r * kt_r;
#pragma unroll
      for (int r = 0; r < 8; ++r)
        t8s[r] = rdlane(wredsum(Kreg[r] * u_r), 63);
    } else if (w == 1) {
      const int r1 = lam >> 3, r2 = lam & 7;
      float acc = 0.0f;
#pragma unroll 4
      for (int s = 0; s < 32; ++s)
        acc = fmaf(KM_s[s*8 + r1], KM_s[s*8 + r2], acc);
#pragma unroll 4
      for (int l = 0; l < 64; ++l)
        acc = fmaf(Kt_s[l*8 + r1] * qv_s[l], Kt_s[l*8 + r2], acc);
      C8_s[lam] = acc + (r1 == r2 ? 1.0f : 0.0f);
      chol8M8();
    }
    bar_lgkm();  // B3 (M8_s, v1t_s visible)

    // ---- P4: per-row y1/g/ag/z update (registers + DPP); wave0 mf tail ----
#pragma unroll
    for (int i = 0; i < 4; ++i) {
      const int s = 4*w + i;
      float4 va = *(const float4*)&v1t_s[s*8];
      float4 vb = *(const float4*)&v1t_s[s*8+4];
      float gg = 0.0f;
#pragma unroll
      for (int r1i = 0; r1i < 8; ++r1i) {
        float4 ma = *(const float4*)&M8_s[r1i*8];
        float4 mb = *(const float4*)&M8_s[r1i*8+4];
        float y = ma.x*va.x+ma.y*va.y+ma.z*va.z+ma.w*va.w
                + mb.x*vb.x+mb.y*vb.y+mb.z*vb.z+mb.w*vb.w;
        gg = fmaf(Kreg[r1i], y, gg);
      }
      float corr = 0.0f;
#pragma unroll
      for (int s2 = 0; s2 < 32; ++s2) {
        float a = wredsum(mcrow[s2] * gg);
        corr = fmaf(mcrow[s2], rdlane(a, 63), corr);
      }
      zreg[i] = zreg[i] - corr - q_r*gg;   // z' (mf added next dyn)
    }
    if (w == 0) {
      float y8[8];
#pragma unroll
      for (int r1i = 0; r1i < 8; ++r1i) {
        float4 ma = *(const float4*)&M8_s[r1i*8];
        float4 mb = *(const float4*)&M8_s[r1i*8+4];
        y8[r1i] = ma.x*t8s[0]+ma.y*t8s[1]+ma.z*t8s[2]+ma.w*t8s[3]
                + mb.x*t8s[4]+mb.y*t8s[5]+mb.z*t8s[6]+mb.w*t8s[7];
      }
      float gvv = 0.0f;
#pragma unroll
      for (int r = 0; r < 8; ++r) gvv = fmaf(Kreg[r], y8[r], gvv);
      float mctg = 0.0f;
#pragma unroll
      for (int s2 = 0; s2 < 32; ++s2) {
        float a = wredsum(mcrow[s2] * gvv);
        mctg = fmaf(mcrow[s2], rdlane(a, 63), mctg);
      }
      const float mf_r = u_r - mctg - q_r*gvv;
      mf_s[lam] = mf_r;
      outp[((size_t)t*B_ + b)*L_ + lam] = mf_r;
    }
    bar_lgkm();  // B4 (mf_s visible for next P1)
  }
}

extern "C" void kernel_launch(void* const* d_in, const int* in_sizes, int n_in,
                              void* d_out, int out_size, void* d_ws, size_t ws_size,
                              hipStream_t stream) {
  (void)in_sizes; (void)n_in; (void)out_size; (void)d_ws; (void)ws_size;
  nlf_kernel<<<dim3(B_), dim3(512), 0, stream>>>(
      (const float*)d_in[0], (const float*)d_in[1], (const float*)d_in[2],
      (const float*)d_in[3], (const float*)d_in[4], (const float*)d_in[5],
      (const float*)d_in[6], (const float*)d_in[7], (const float*)d_in[8],
      (const float*)d_in[9], (const float*)d_in[10], (float*)d_out);
}

// Round 8
// 11485.900 us; speedup vs baseline: 1.4218x; 1.0086x over previous
//
#include <hip/hip_runtime.h>
#include <cstdint>
#include <cstddef>

namespace {
constexpr int T_ = 500, S_ = 32, B_ = 128, L_ = 64, R_ = 8;

__device__ __forceinline__ float rdlane(float v, int l) {
  return __int_as_float(__builtin_amdgcn_readlane(__float_as_int(v), l));
}
template<int CTRL, int RM>
__device__ __forceinline__ float dppadd(float v) {
  int t = __builtin_amdgcn_update_dpp(0, __float_as_int(v), CTRL, RM, 0xf, false);
  return v + __int_as_float(t);
}
// full 64-lane sum; total lands in lane 63 (VALU-only, no DS)
__device__ __forceinline__ float wredsum(float v) {
  v = dppadd<0x111, 0xf>(v);   // row_shr:1
  v = dppadd<0x112, 0xf>(v);   // row_shr:2
  v = dppadd<0x114, 0xf>(v);   // row_shr:4
  v = dppadd<0x118, 0xf>(v);   // row_shr:8
  v = dppadd<0x142, 0xa>(v);   // row_bcast:15 -> rows 1,3
  v = dppadd<0x143, 0xc>(v);   // row_bcast:31 -> rows 2,3
  return v;
}
__device__ __forceinline__ float wsum(float v) {  // all-lanes result (step0 only)
  v += __shfl_xor(v, 1);  v += __shfl_xor(v, 2);  v += __shfl_xor(v, 4);
  v += __shfl_xor(v, 8);  v += __shfl_xor(v, 16); v += __shfl_xor(v, 32);
  return v;
}
__device__ __forceinline__ void gload16(const float* g, float* l) {
  __builtin_amdgcn_global_load_lds((const __attribute__((address_space(1))) uint32_t*)g,
                                   (__attribute__((address_space(3))) uint32_t*)l,
                                   16, 0, 0);
}
// barrier that drains LDS ops but lets global loads/stores ride (vmcnt untouched)
__device__ __forceinline__ void bar_lgkm() {
  asm volatile("s_waitcnt lgkmcnt(0)\n\ts_barrier" ::: "memory");
}
}  // namespace

// One block per batch element b. 512 threads = 8 waves; wave w owns ensemble
// rows 4w..4w+3. z' lives in LDS (stride-68 rows, b128-broadcast reads);
// Mc row + A row live in registers. waves_per_eu(2,2): only 1 block/CU can
// ever run (grid 128 <= 256 CUs), so cap occupancy at 2 waves/SIMD and let
// the allocator use up to 256 VGPRs instead of spilling at 128.
__global__
__attribute__((amdgpu_flat_work_group_size(512, 512)))
__attribute__((amdgpu_waves_per_eu(2, 2)))
void nlf_kernel(
    const float* __restrict__ m0p, const float* __restrict__ q0p,
    const float* __restrict__ qp,  const float* __restrict__ kp,
    const float* __restrict__ Kp,  const float* __restrict__ Ap,
    const float* __restrict__ wp0p, const float* __restrict__ wf0p,
    const float* __restrict__ wp1p, const float* __restrict__ wp2p,
    const float* __restrict__ wfp,  float* __restrict__ outp)
{
  __shared__ __align__(16) float z_s[S_*68];      // carry z' (z - mf)
  __shared__ __align__(16) float Mc_s[L_*33];     // M_c[l][s]
  __shared__ __align__(16) float uni[8*68];       // mp partial sums
  __shared__ __align__(16) float wp1b[2][S_*S_];
  __shared__ __align__(16) float wp2b[2][S_*L_];
  __shared__ __align__(16) float wf_s[S_*R_];
  __shared__ __align__(16) float Kt_s[L_*R_];
  __shared__ __align__(16) float v1t_s[S_*R_];
  __shared__ __align__(16) float KM_s[S_*R_];     // [s*8+r]
  __shared__ __align__(16) float M8_s[64];
  __shared__ __align__(16) float C8_s[64];
  __shared__ __align__(16) float tk_s[S_];        // Mc^T k_t
  __shared__ __align__(16) float mf_s[L_];
  __shared__ __align__(16) float qv_s[L_];
  __shared__ __align__(16) float q0v_s[L_];

  const int tid = threadIdx.x;
  const int lam = tid & 63;
  const int w   = tid >> 6;
  const int b   = blockIdx.x;

  float Areg[64];
#pragma unroll
  for (int j4 = 0; j4 < 16; ++j4) {
    float4 a4 = *(const float4*)(Ap + (size_t)lam*64 + j4*4);
    Areg[4*j4+0]=a4.x; Areg[4*j4+1]=a4.y; Areg[4*j4+2]=a4.z; Areg[4*j4+3]=a4.w;
  }
  const float q_r  = qp[lam];
  const float qs_r = sqrtf(q_r);
  const float q0_r = q0p[lam];
  const float m0_r = m0p[lam];
  if (tid < 64) { qv_s[tid] = q_r; q0v_s[tid] = q0_r; }

  float Kreg[8];
  {
    const float* kb = Kp + (size_t)b*(L_*R_) + lam*R_;
    float4 ka = *(const float4*)kb, kb4 = *(const float4*)(kb+4);
    Kreg[0]=ka.x;Kreg[1]=ka.y;Kreg[2]=ka.z;Kreg[3]=ka.w;
    Kreg[4]=kb4.x;Kreg[5]=kb4.y;Kreg[6]=kb4.z;Kreg[7]=kb4.w;
  }
  float kt_r = kp[(size_t)b*L_ + lam];

  // ---- prologue async loads ----
  if (w == 0) {                       // wp1[0] -> wp1b[1]
#pragma unroll
    for (int m = 0; m < 4; ++m) {
      int f = m*256 + lam*4, s = f >> 5, c = f & 31;
      gload16(wp1p + ((size_t)s*B_ + b)*S_ + c, &wp1b[1][f]);
    }
  } else if (w == 1 || w == 2) {      // wp2[0] -> wp2b[1]
#pragma unroll
    for (int m = 0; m < 4; ++m) {
      int f = (w-1)*1024 + m*256 + lam*4, s = f >> 6, c = f & 63;
      gload16(wp2p + ((size_t)s*B_ + b)*L_ + c, &wp2b[1][f]);
    }
  } else if (w == 3) {                // wf0 -> wf_s ; K[0] -> Kt_s
    { int f = lam*4, s = f >> 3, c = f & 7;
      gload16(wf0p + ((size_t)s*B_ + b)*R_ + c, &wf_s[f]); }
#pragma unroll
    for (int m = 0; m < 2; ++m) {
      int f = m*256 + lam*4;
      gload16(Kp + (size_t)b*(L_*R_) + f, &Kt_s[f]);
    }
  } else if (w == 4 || w == 5) {      // w_p0 -> wp2b[0]
#pragma unroll
    for (int m = 0; m < 4; ++m) {
      int f = (w-4)*1024 + m*256 + lam*4, s = f >> 6, c = f & 63;
      gload16(wp0p + ((size_t)s*B_ + b)*L_ + c, &wp2b[0][f]);
    }
  }
  __syncthreads();

  // 8x8 SPD: C8_s -> M8_s = inv(C8) via in-register Cholesky (rows in lanes 0-7)
  auto chol8M8 = [&]() {
    const int i8 = lam & 7;
    float c8[8], rd8 = 0.0f;
#pragma unroll
    for (int k = 0; k < 8; ++k) c8[k] = C8_s[i8*8 + k];
#pragma unroll
    for (int j = 0; j < 8; ++j) {
      float dj = rdlane(c8[j], j);
      float rinv = rsqrtf(dj);
      if (i8 == j) rd8 = rinv;
      c8[j] *= rinv;
#pragma unroll
      for (int k = j+1; k < 8; ++k)
        c8[k] = fmaf(-rdlane(c8[j], k), c8[j], c8[k]);
    }
    float w8[8];
#pragma unroll
    for (int i = 0; i < 8; ++i) {
      float sacc = (i == i8) ? 1.0f : 0.0f;
#pragma unroll
      for (int k = 0; k < i; ++k)
        sacc = fmaf(-rdlane(c8[k], i), w8[k], sacc);
      w8[i] = sacc * rdlane(rd8, i);
    }
#pragma unroll
    for (int i = 0; i < 8; ++i) {
      float msum = 0.0f;
#pragma unroll
      for (int k = 0; k < 8; ++k)
        msum = fmaf(rdlane(w8[k], i), w8[k], msum);
      if (lam < 8) M8_s[i*8 + lam] = msum;
    }
  };

  // ================= step 0 =================
  {
    const float Pp = q0_r;
    const float h0 = m0_r / Pp + kt_r;
    if (w == 0) {
      const int r1 = lam >> 3, r2 = lam & 7;
      float acc = 0.0f;
#pragma unroll 4
      for (int l = 0; l < 64; ++l)
        acc = fmaf(Kt_s[l*8 + r1] * q0v_s[l], Kt_s[l*8 + r2], acc);
      C8_s[lam] = acc + (r1 == r2 ? 1.0f : 0.0f);
      chol8M8();
      float t8[8];
#pragma unroll
      for (int r = 0; r < 8; ++r) t8[r] = wsum(Pp * Kreg[r] * h0);
      float acc2 = 0.0f;
#pragma unroll
      for (int r1i = 0; r1i < 8; ++r1i) {
        float4 ma = *(const float4*)&M8_s[r1i*8];
        float4 mb = *(const float4*)&M8_s[r1i*8+4];
        float y = ma.x*t8[0]+ma.y*t8[1]+ma.z*t8[2]+ma.w*t8[3]
                + mb.x*t8[4]+mb.y*t8[5]+mb.z*t8[6]+mb.w*t8[7];
        acc2 = fmaf(Kreg[r1i], y, acc2);
      }
      float m0f = Pp*h0 - Pp*acc2;
      mf_s[lam] = m0f;
      outp[(size_t)b*L_ + lam] = m0f;
    }
    __syncthreads();

    const float qs0 = sqrtf(q0_r);
#pragma unroll
    for (int i = 0; i < 4; ++i) {
      const int s = 4*w + i;
      float zp = qs0 * wp2b[0][s*64 + lam];
      float v1[8];
#pragma unroll
      for (int r = 0; r < 8; ++r)
        v1[r] = wsum(Kreg[r] * zp) + wf_s[s*8 + r];
      float acc = 0.0f;
#pragma unroll
      for (int r1i = 0; r1i < 8; ++r1i) {
        float4 ma = *(const float4*)&M8_s[r1i*8];
        float4 mb = *(const float4*)&M8_s[r1i*8+4];
        float y = ma.x*v1[0]+ma.y*v1[1]+ma.z*v1[2]+ma.w*v1[3]
                + mb.x*v1[4]+mb.y*v1[5]+mb.z*v1[6]+mb.w*v1[7];
        acc = fmaf(Kreg[r1i], y, acc);
      }
      z_s[s*68 + lam] = zp - Pp*acc;   // z' excludes m_f (added in next dyn)
    }
  }
  __syncthreads();

  // ================= steps 1..T-1 =================
  for (int t = 1; t < T_; ++t) {
    const int cb = t & 1, nb = cb ^ 1;

    // per-lane K/k reload (global; hidden under P1, used from P2 on)
    {
      const float* kb = Kp + ((size_t)t*B_ + b)*(L_*R_) + lam*R_;
      float4 ka = *(const float4*)kb, kb4 = *(const float4*)(kb+4);
      Kreg[0]=ka.x;Kreg[1]=ka.y;Kreg[2]=ka.z;Kreg[3]=ka.w;
      Kreg[4]=kb4.x;Kreg[5]=kb4.y;Kreg[6]=kb4.z;Kreg[7]=kb4.w;
      kt_r = kp[((size_t)t*B_ + b)*L_ + lam];
    }

    // ---- P1: dyn on z = z' + mf (z rows via b128 LDS broadcast) ----
    float dmf = 0.0f;
#pragma unroll
    for (int j4 = 0; j4 < 16; ++j4) {
      float4 m4 = *(const float4*)&mf_s[4*j4];
      dmf = fmaf(m4.x, Areg[4*j4+0], dmf);
      dmf = fmaf(m4.y, Areg[4*j4+1], dmf);
      dmf = fmaf(m4.z, Areg[4*j4+2], dmf);
      dmf = fmaf(m4.w, Areg[4*j4+3], dmf);
    }
    const float mfl = mf_s[lam];
    float zn[4];
#pragma unroll
    for (int i = 0; i < 4; ++i) {
      const int s = 4*w + i;
      float a0=0,a1=0,a2=0,a3=0;
#pragma unroll
      for (int j4 = 0; j4 < 16; ++j4) {
        float4 zb = *(const float4*)&z_s[s*68 + 4*j4];
        a0 = fmaf(zb.x, Areg[4*j4+0], a0);
        a1 = fmaf(zb.y, Areg[4*j4+1], a1);
        a2 = fmaf(zb.z, Areg[4*j4+2], a2);
        a3 = fmaf(zb.w, Areg[4*j4+3], a3);
      }
      float x = ((a0+a1)+(a2+a3)) + dmf;
      float e = __expf(2.0f*x);
      float tnh = 1.0f - 2.0f/(e + 1.0f);
      zn[i] = (z_s[s*68 + lam] + mfl) + 0.1f*tnh;
    }
    uni[w*68 + lam] = zn[0]+zn[1]+zn[2]+zn[3];
    bar_lgkm();  // B1

    // ---- P0: async prefetch; drains at B2 (syncthreads) ----
    if (w == 0) {
      if (t < T_-1) {
#pragma unroll
        for (int m = 0; m < 4; ++m) {
          int f = m*256 + lam*4, s = f >> 5, c = f & 31;
          gload16(wp1p + (((size_t)t*S_ + s)*B_ + b)*S_ + c, &wp1b[nb][f]);
        }
      }
    } else if (w == 1 || w == 2) {
      if (t < T_-1) {
#pragma unroll
        for (int m = 0; m < 4; ++m) {
          int f = (w-1)*1024 + m*256 + lam*4, s = f >> 6, c = f & 63;
          gload16(wp2p + (((size_t)t*S_ + s)*B_ + b)*L_ + c, &wp2b[nb][f]);
        }
      }
    } else if (w == 3) {
      { int f = lam*4, s = f >> 3, c = f & 7;
        gload16(wfp + (((size_t)(t-1)*S_ + s)*B_ + b)*R_ + c, &wf_s[f]); }
#pragma unroll
      for (int m = 0; m < 2; ++m) {
        int f = m*256 + lam*4;
        gload16(Kp + ((size_t)t*B_ + b)*(L_*R_) + f, &Kt_s[f]);
      }
    }

    // ---- P2: m_p, M_c, KM = K^T Mc, tk = Mc^T k_t (DPP) ----
    float mp = 0.0f;
#pragma unroll
    for (int ww = 0; ww < 8; ++ww) mp += uni[ww*68 + lam];
    mp *= 0.03125f;
    float mcv[4];
#pragma unroll
    for (int i = 0; i < 4; ++i) {
      const int s = 4*w + i;
      mcv[i] = (zn[i] - mp) * 0.17677669529663689f;
      Mc_s[lam*33 + s] = mcv[i];
      float tkv = wredsum(mcv[i] * kt_r);
      float kmv[8];
#pragma unroll
      for (int r = 0; r < 8; ++r) kmv[r] = wredsum(mcv[i] * Kreg[r]);
      if (lam == 63) {
        tk_s[s] = tkv;
        *(float4*)&KM_s[s*8]   = make_float4(kmv[0],kmv[1],kmv[2],kmv[3]);
        *(float4*)&KM_s[s*8+4] = make_float4(kmv[4],kmv[5],kmv[6],kmv[7]);
      }
    }
    __syncthreads();  // B2 (full: drains prefetch vmcnt)

    // per-lane Mc row into registers (reused by P3 and P4)
    float mcrow[32];
#pragma unroll
    for (int s2 = 0; s2 < 32; ++s2) mcrow[s2] = Mc_s[lam*33 + s2];

    // ---- P3: zprows + wave0 {u, t8} + wave1 {C8, M8} ----
    float zloc[4];
    float u_r = 0.0f, t8s[8];
#pragma unroll
    for (int r = 0; r < 8; ++r) t8s[r] = 0.0f;
#pragma unroll
    for (int i = 0; i < 4; ++i) {
      const int s = 4*w + i;
      float acc = 0.0f;
#pragma unroll
      for (int p4 = 0; p4 < 32; p4 += 4) {
        float4 wb = *(const float4*)&wp1b[cb][s*32 + p4];
        acc = fmaf(mcrow[p4+0], wb.x, acc);
        acc = fmaf(mcrow[p4+1], wb.y, acc);
        acc = fmaf(mcrow[p4+2], wb.z, acc);
        acc = fmaf(mcrow[p4+3], wb.w, acc);
      }
      float zp = acc + qs_r * wp2b[cb][s*64 + lam];
      zloc[i] = zp;
      float vv[8];
#pragma unroll
      for (int r = 0; r < 8; ++r) vv[r] = wredsum(Kreg[r] * zp);
      if (lam == 63) {
        float4 wfa = *(const float4*)&wf_s[s*8];
        float4 wfb = *(const float4*)&wf_s[s*8+4];
        *(float4*)&v1t_s[s*8]   = make_float4(vv[0]+wfa.x, vv[1]+wfa.y,
                                              vv[2]+wfa.z, vv[3]+wfa.w);
        *(float4*)&v1t_s[s*8+4] = make_float4(vv[4]+wfb.x, vv[5]+wfb.y,
                                              vv[6]+wfb.z, vv[7]+wfb.w);
      }
    }
    if (w == 0) {
      // u = m_p + Mc tk + q k_t (Woodbury); t8 = K^T u
      float mctk = 0.0f;
#pragma unroll
      for (int s4 = 0; s4 < 32; s4 += 4) {
        float4 tb = *(const float4*)&tk_s[s4];
        mctk = fmaf(mcrow[s4+0], tb.x, mctk);
        mctk = fmaf(mcrow[s4+1], tb.y, mctk);
        mctk = fmaf(mcrow[s4+2], tb.z, mctk);
        mctk = fmaf(mcrow[s4+3], tb.w, mctk);
      }
      u_r = mp + mctk + q_r * kt_r;
#pragma unroll
      for (int r = 0; r < 8; ++r)
        t8s[r] = rdlane(wredsum(Kreg[r] * u_r), 63);
    } else if (w == 1) {
      const int r1 = lam >> 3, r2 = lam & 7;
      float acc = 0.0f;
#pragma unroll 4
      for (int s = 0; s < 32; ++s)
        acc = fmaf(KM_s[s*8 + r1], KM_s[s*8 + r2], acc);
#pragma unroll 4
      for (int l = 0; l < 64; ++l)
        acc = fmaf(Kt_s[l*8 + r1] * qv_s[l], Kt_s[l*8 + r2], acc);
      C8_s[lam] = acc + (r1 == r2 ? 1.0f : 0.0f);
      chol8M8();
    }
    bar_lgkm();  // B3 (M8_s, v1t_s visible)

    // ---- P4: y1/g per row, then s2-outer corr (4 indep DPP chains/iter) ----
    float gg[4];
#pragma unroll
    for (int i = 0; i < 4; ++i) {
      const int s = 4*w + i;
      float4 va = *(const float4*)&v1t_s[s*8];
      float4 vb = *(const float4*)&v1t_s[s*8+4];
      float g = 0.0f;
#pragma unroll
      for (int r1i = 0; r1i < 8; ++r1i) {
        float4 ma = *(const float4*)&M8_s[r1i*8];
        float4 mb = *(const float4*)&M8_s[r1i*8+4];
        float y = ma.x*va.x+ma.y*va.y+ma.z*va.z+ma.w*va.w
                + mb.x*vb.x+mb.y*vb.y+mb.z*vb.z+mb.w*vb.w;
        g = fmaf(Kreg[r1i], y, g);
      }
      gg[i] = g;
    }
    {
      float c0=0.0f, c1=0.0f, c2=0.0f, c3=0.0f;
#pragma unroll
      for (int s2 = 0; s2 < 32; ++s2) {
        const float mcl = mcrow[s2];
        float a0 = wredsum(mcl * gg[0]);
        float a1 = wredsum(mcl * gg[1]);
        float a2 = wredsum(mcl * gg[2]);
        float a3 = wredsum(mcl * gg[3]);
        c0 = fmaf(mcl, rdlane(a0, 63), c0);
        c1 = fmaf(mcl, rdlane(a1, 63), c1);
        c2 = fmaf(mcl, rdlane(a2, 63), c2);
        c3 = fmaf(mcl, rdlane(a3, 63), c3);
      }
      const int sb = 4*w;
      z_s[(sb+0)*68 + lam] = zloc[0] - c0 - q_r*gg[0];
      z_s[(sb+1)*68 + lam] = zloc[1] - c1 - q_r*gg[1];
      z_s[(sb+2)*68 + lam] = zloc[2] - c2 - q_r*gg[2];
      z_s[(sb+3)*68 + lam] = zloc[3] - c3 - q_r*gg[3];
    }
    if (w == 0) {
      float y8[8];
#pragma unroll
      for (int r1i = 0; r1i < 8; ++r1i) {
        float4 ma = *(const float4*)&M8_s[r1i*8];
        float4 mb = *(const float4*)&M8_s[r1i*8+4];
        y8[r1i] = ma.x*t8s[0]+ma.y*t8s[1]+ma.z*t8s[2]+ma.w*t8s[3]
                + mb.x*t8s[4]+mb.y*t8s[5]+mb.z*t8s[6]+mb.w*t8s[7];
      }
      float gvv = 0.0f;
#pragma unroll
      for (int r = 0; r < 8; ++r) gvv = fmaf(Kreg[r], y8[r], gvv);
      float mctg = 0.0f;
#pragma unroll
      for (int s2 = 0; s2 < 32; ++s2) {
        float a = wredsum(mcrow[s2] * gvv);
        mctg = fmaf(mcrow[s2], rdlane(a, 63), mctg);
      }
      const float mf_r = u_r - mctg - q_r*gvv;
      mf_s[lam] = mf_r;
      outp[((size_t)t*B_ + b)*L_ + lam] = mf_r;
    }
    bar_lgkm();  // B4 (mf_s, z_s visible for next P1)
  }
}

extern "C" void kernel_launch(void* const* d_in, const int* in_sizes, int n_in,
                              void* d_out, int out_size, void* d_ws, size_t ws_size,
                              hipStream_t stream) {
  (void)in_sizes; (void)n_in; (void)out_size; (void)d_ws; (void)ws_size;
  nlf_kernel<<<dim3(B_), dim3(512), 0, stream>>>(
      (const float*)d_in[0], (const float*)d_in[1], (const float*)d_in[2],
      (const float*)d_in[3], (const float*)d_in[4], (const float*)d_in[5],
      (const float*)d_in[6], (const float*)d_in[7], (const float*)d_in[8],
      (const float*)d_in[9], (const float*)d_in[10], (float*)d_out);
}